// Round 3
// baseline (1462.824 us; speedup 1.0000x reference)
//
#include <hip/hip_runtime.h>
#include <hip/hip_bf16.h>
#include <math.h>

// ---------------- problem constants ----------------
#define FN 360            // nodes per graph == features
#define NG 128            // graphs
#define NN 46080          // NG*FN
#define CH 128            // hidden channels
#define NE 1000000        // edges
#define TRI 64980         // FN*(FN+1)/2
#define D1 65364          // TRI + 3*CH
#define ZLD 65376         // D1 padded to multiple of 32 (zeroed tail)
#define H1 512
#define H2 256
#define EPS 1e-5f

typedef unsigned short u16;
typedef __attribute__((ext_vector_type(8))) short bf16x8;
typedef __attribute__((ext_vector_type(4))) float f32x4;

__device__ __forceinline__ float bf2f(u16 v) {
  union { unsigned u; float f; } x; x.u = ((unsigned)v) << 16; return x.f;
}
__device__ __forceinline__ u16 f2bf(float f) {
  union { float f; unsigned u; } x; x.f = f;
  unsigned r = x.u + 0x7fffu + ((x.u >> 16) & 1u);   // RNE
  return (u16)(r >> 16);
}
__device__ __forceinline__ bf16x8 bzero8() {
  bf16x8 z;
#pragma unroll
  for (int j = 0; j < 8; j++) z[j] = 0;
  return z;
}

// ---------------- workspace layout (bytes) ----------------
static const size_t A32_OFF = 0;                       // f32 [NG*FN*FN]  (66,355,200)
static const size_t AB_OFF  = 66355200;                // bf16 [NG*FN*FN] (33,177,600)
static const size_t DEG_OFF = 99532800;                // f32 [NN]
static const size_t P_OFF   = 99717120;                // bf16 [NN*CH]
static const size_t HA_OFF  = 111513600;               // bf16 [NN*CH]
static const size_t HB_OFF  = 123310080;               // bf16 [NN*CH]
static const size_t HP_OFF  = 135106560;               // f32 [NG*384]  -> ends 135,303,168
// region0 reuse (after k_aconv consumes A32):
static const size_t Z_OFF   = 0;                       // bf16 [NG*ZLD] (16,736,256)
static const size_t Y1_OFF  = 16736256;                // f32 [NG*H1]
static const size_t A1_OFF  = Y1_OFF + 262144;         // bf16 [NG*H1]
static const size_t Y2_OFF  = A1_OFF + 131072;         // f32 [NG*H2]
static const size_t A2_OFF  = Y2_OFF + 131072;         // bf16 [NG*H2]
static const size_t Y3_OFF  = A2_OFF + 65536;          // f32 [NG*H2]
static const size_t A3_OFF  = Y3_OFF + 131072;         // bf16 [NG*H2]
static const size_t PART_OFF= A3_OFF + 65536;          // f32 [32*NG*H1] -> ends 25,911,296

// ---------------- graph-structure kernels ----------------
__global__ void k_deg(const int* __restrict__ dst, float* __restrict__ deg) {
  int e = blockIdx.x * 256 + threadIdx.x;
  if (e < NE) atomicAdd(&deg[dst[e]], 1.0f);
}

__global__ void k_dinv(float* __restrict__ deg) {
  int i = blockIdx.x * 256 + threadIdx.x;
  if (i < NN) deg[i] = rsqrtf(deg[i] + 1.0f);   // +1: self loop
}

__global__ void k_abuild(const int* __restrict__ src, const int* __restrict__ dst,
                         const float* __restrict__ dinv, float* __restrict__ A) {
  int e = blockIdx.x * 256 + threadIdx.x;
  if (e >= NE) return;
  int s = src[e], d = dst[e];
  int g = d / FN;
  int ls = s - g * FN, ld = d - g * FN;
  atomicAdd(&A[(size_t)g * FN * FN + (size_t)ld * FN + ls], dinv[s] * dinv[d]);
}

// fuse self-loop diagonal into the f32->bf16 conversion
__global__ void k_aconv(const float* __restrict__ A, u16* __restrict__ Ab,
                        const float* __restrict__ dinv) {
  int idx = blockIdx.x * 256 + threadIdx.x;   // < NG*FN*FN
  float v = A[idx];
  int rc = idx % (FN * FN);
  int r = rc / FN, c = rc % FN;
  if (r == c) {
    int g = idx / (FN * FN);
    float dv = dinv[g * FN + r];
    v += dv * dv;
  }
  Ab[idx] = f2bf(v);
}

// ------- MFMA GEMM (f32 A input): P[M][128] = X[M][K] @ W[K][128] -------
// Block 256 = 4 waves; BM=64, BN=128; per-wave 32x64. K%8==0.
__global__ __launch_bounds__(256) void k_gemm_xw_f32(
    const float* __restrict__ X, const float* __restrict__ W,
    u16* __restrict__ P, int K) {
  int wid = threadIdx.x >> 6, lane = threadIdx.x & 63;
  int quad = lane >> 4, l16 = lane & 15;
  int m0 = blockIdx.x * 64 + (wid & 1) * 32;
  int n0 = (wid >> 1) * 64;
  f32x4 acc[2][4];
#pragma unroll
  for (int i = 0; i < 2; i++)
#pragma unroll
    for (int j = 0; j < 4; j++) acc[i][j] = (f32x4){0,0,0,0};
  for (int k0 = 0; k0 < K; k0 += 32) {
    int kk = k0 + quad * 8;
    bool kin = kk < K;
    bf16x8 af[2];
#pragma unroll
    for (int tm = 0; tm < 2; tm++) {
      int row = m0 + tm * 16 + l16;
      bf16x8 a = bzero8();
      if (kin) {
        f32x4 va = *(const f32x4*)(X + (size_t)row * K + kk);
        f32x4 vb = *(const f32x4*)(X + (size_t)row * K + kk + 4);
#pragma unroll
        for (int j = 0; j < 4; j++) { a[j] = (short)f2bf(va[j]); a[4+j] = (short)f2bf(vb[j]); }
      }
      af[tm] = a;
    }
    bf16x8 bfr[4];
#pragma unroll
    for (int tn = 0; tn < 4; tn++) {
      int col = n0 + tn * 16 + l16;
      bf16x8 b = bzero8();
#pragma unroll
      for (int j = 0; j < 8; j++) {
        int k = kk + j;
        if (k < K) b[j] = (short)f2bf(W[(size_t)k * CH + col]);
      }
      bfr[tn] = b;
    }
#pragma unroll
    for (int tm = 0; tm < 2; tm++)
#pragma unroll
      for (int tn = 0; tn < 4; tn++)
        acc[tm][tn] = __builtin_amdgcn_mfma_f32_16x16x32_bf16(af[tm], bfr[tn], acc[tm][tn], 0, 0, 0);
  }
#pragma unroll
  for (int tm = 0; tm < 2; tm++)
#pragma unroll
    for (int tn = 0; tn < 4; tn++) {
      int col = n0 + tn * 16 + l16;
      int rowb = m0 + tm * 16 + quad * 4;
#pragma unroll
      for (int r = 0; r < 4; r++)
        P[(size_t)(rowb + r) * CH + col] = f2bf(acc[tm][tn][r]);
    }
}

// ------- MFMA GEMM (bf16 A input): P = X[M][K] @ W[K][128], W f32 -------
__global__ __launch_bounds__(256) void k_gemm_xw_bf16(
    const u16* __restrict__ X, const float* __restrict__ W,
    u16* __restrict__ P, int K) {
  int wid = threadIdx.x >> 6, lane = threadIdx.x & 63;
  int quad = lane >> 4, l16 = lane & 15;
  int m0 = blockIdx.x * 64 + (wid & 1) * 32;
  int n0 = (wid >> 1) * 64;
  f32x4 acc[2][4];
#pragma unroll
  for (int i = 0; i < 2; i++)
#pragma unroll
    for (int j = 0; j < 4; j++) acc[i][j] = (f32x4){0,0,0,0};
  for (int k0 = 0; k0 < K; k0 += 32) {
    int kk = k0 + quad * 8;
    bool kin = kk < K;
    bf16x8 af[2];
#pragma unroll
    for (int tm = 0; tm < 2; tm++) {
      int row = m0 + tm * 16 + l16;
      af[tm] = kin ? *(const bf16x8*)(X + (size_t)row * K + kk) : bzero8();
    }
    bf16x8 bfr[4];
#pragma unroll
    for (int tn = 0; tn < 4; tn++) {
      int col = n0 + tn * 16 + l16;
      bf16x8 b = bzero8();
#pragma unroll
      for (int j = 0; j < 8; j++) {
        int k = kk + j;
        if (k < K) b[j] = (short)f2bf(W[(size_t)k * CH + col]);
      }
      bfr[tn] = b;
    }
#pragma unroll
    for (int tm = 0; tm < 2; tm++)
#pragma unroll
      for (int tn = 0; tn < 4; tn++)
        acc[tm][tn] = __builtin_amdgcn_mfma_f32_16x16x32_bf16(af[tm], bfr[tn], acc[tm][tn], 0, 0, 0);
  }
#pragma unroll
  for (int tm = 0; tm < 2; tm++)
#pragma unroll
    for (int tn = 0; tn < 4; tn++) {
      int col = n0 + tn * 16 + l16;
      int rowb = m0 + tm * 16 + quad * 4;
#pragma unroll
      for (int r = 0; r < 4; r++)
        P[(size_t)(rowb + r) * CH + col] = f2bf(acc[tm][tn][r]);
    }
}

// ------- batched aggregation: H_g = tanh(A_g[360x360] @ P_g[360x128] + bias) -------
__global__ __launch_bounds__(256) void k_gemm_agg(
    const u16* __restrict__ Ab, const u16* __restrict__ P,
    const float* __restrict__ bias, u16* __restrict__ Hout) {
  int g = blockIdx.z;
  int wid = threadIdx.x >> 6, lane = threadIdx.x & 63;
  int quad = lane >> 4, l16 = lane & 15;
  int m0 = blockIdx.y * 64 + (wid & 1) * 32;
  int n0 = blockIdx.x * 64 + (wid >> 1) * 32;
  const u16* Ag = Ab + (size_t)g * FN * FN;
  const u16* Pg = P + (size_t)g * FN * CH;
  f32x4 acc[2][2];
#pragma unroll
  for (int i = 0; i < 2; i++)
#pragma unroll
    for (int j = 0; j < 2; j++) acc[i][j] = (f32x4){0,0,0,0};
  for (int k0 = 0; k0 < FN; k0 += 32) {
    int kk = k0 + quad * 8;
    bool kin = kk < FN;
    bf16x8 af[2];
#pragma unroll
    for (int tm = 0; tm < 2; tm++) {
      int row = m0 + tm * 16 + l16;
      af[tm] = (kin && row < FN) ? *(const bf16x8*)(Ag + (size_t)row * FN + kk) : bzero8();
    }
    bf16x8 bfr[2];
#pragma unroll
    for (int tn = 0; tn < 2; tn++) {
      int col = n0 + tn * 16 + l16;
      bf16x8 b = bzero8();
#pragma unroll
      for (int j = 0; j < 8; j++) {
        int k = kk + j;
        if (k < FN) b[j] = (short)Pg[(size_t)k * CH + col];
      }
      bfr[tn] = b;
    }
#pragma unroll
    for (int tm = 0; tm < 2; tm++)
#pragma unroll
      for (int tn = 0; tn < 2; tn++)
        acc[tm][tn] = __builtin_amdgcn_mfma_f32_16x16x32_bf16(af[tm], bfr[tn], acc[tm][tn], 0, 0, 0);
  }
#pragma unroll
  for (int tm = 0; tm < 2; tm++)
#pragma unroll
    for (int tn = 0; tn < 2; tn++) {
      int col = n0 + tn * 16 + l16;
      float bc = bias[col];
      int rowb = m0 + tm * 16 + quad * 4;
#pragma unroll
      for (int r = 0; r < 4; r++) {
        int row = rowb + r;
        if (row < FN)
          Hout[(size_t)(g * FN + row) * CH + col] = f2bf(tanhf(acc[tm][tn][r] + bc));
      }
    }
}

// ------- big GEMM: part[s] = Z[128][chunk] @ W1[chunk][512] (W1 f32), split-K -------
__global__ __launch_bounds__(256) void k_gemm_big(
    const u16* __restrict__ Z, const float* __restrict__ W1f, float* __restrict__ part) {
  int s = blockIdx.z;
  int wid = threadIdx.x >> 6, lane = threadIdx.x & 63;
  int quad = lane >> 4, l16 = lane & 15;
  int m0 = blockIdx.x * 64 + (wid & 1) * 32;
  int n0 = blockIdx.y * 64 + (wid >> 1) * 32;
  int kbeg = s * 2048;
  int kend = (ZLD < kbeg + 2048) ? ZLD : (kbeg + 2048);
  f32x4 acc[2][2];
#pragma unroll
  for (int i = 0; i < 2; i++)
#pragma unroll
    for (int j = 0; j < 2; j++) acc[i][j] = (f32x4){0,0,0,0};
  for (int k0 = kbeg; k0 < kend; k0 += 32) {
    int kk = k0 + quad * 8;
    bf16x8 af[2];
#pragma unroll
    for (int tm = 0; tm < 2; tm++) {
      int row = m0 + tm * 16 + l16;               // < 128
      af[tm] = *(const bf16x8*)(Z + (size_t)row * ZLD + kk);
    }
    bf16x8 bfr[2];
#pragma unroll
    for (int tn = 0; tn < 2; tn++) {
      int col = n0 + tn * 16 + l16;
      bf16x8 b = bzero8();
#pragma unroll
      for (int j = 0; j < 8; j++) {
        int k = kk + j;
        if (k < D1) b[j] = (short)f2bf(W1f[(size_t)k * H1 + col]);
      }
      bfr[tn] = b;
    }
#pragma unroll
    for (int tm = 0; tm < 2; tm++)
#pragma unroll
      for (int tn = 0; tn < 2; tn++)
        acc[tm][tn] = __builtin_amdgcn_mfma_f32_16x16x32_bf16(af[tm], bfr[tn], acc[tm][tn], 0, 0, 0);
  }
#pragma unroll
  for (int tm = 0; tm < 2; tm++)
#pragma unroll
    for (int tn = 0; tn < 2; tn++) {
      int col = n0 + tn * 16 + l16;
      int rowb = m0 + tm * 16 + quad * 4;
#pragma unroll
      for (int r = 0; r < 4; r++)
        part[((size_t)s * NG + rowb + r) * H1 + col] = acc[tm][tn][r];
    }
}

__global__ void k_red(const float* __restrict__ part, const float* __restrict__ b1,
                      float* __restrict__ y1) {
  int idx = blockIdx.x * 256 + threadIdx.x;       // < 65536
  float s = 0.f;
#pragma unroll 8
  for (int i = 0; i < 32; i++) s += part[(size_t)i * 65536 + idx];
  y1[idx] = s + b1[idx & (H1 - 1)];
}

// ---------------- pooling / batch-norm kernels ----------------
__global__ void k_pool(const u16* __restrict__ h, float* __restrict__ hp, int layer) {
  int g = blockIdx.x, c = threadIdx.x;            // block 128
  float s = 0.f;
  for (int r = 0; r < FN; r++) s += bf2f(h[(size_t)(g * FN + r) * CH + c]);
  hp[g * 384 + layer * CH + c] = s * (1.0f / FN);
}

__global__ void k_hbn(const float* __restrict__ hp, const float* __restrict__ gam,
                      const float* __restrict__ bet, u16* __restrict__ z) {
  int c = threadIdx.x;                            // block 384
  float s = 0.f, ss = 0.f;
  for (int m = 0; m < NG; m++) { float v = hp[m * 384 + c]; s += v; ss += v * v; }
  float mean = s * (1.0f / NG);
  float var = fmaxf(ss * (1.0f / NG) - mean * mean, 0.f);
  float rstd = rsqrtf(var + EPS);
  float ga = gam[c] * rstd;
  float bb = bet[c] - mean * ga;
  for (int m = 0; m < NG; m++)
    z[(size_t)m * ZLD + TRI + c] = f2bf(hp[m * 384 + c] * ga + bb);
}

// triu gather + BN of raw connectome -> z[:, 0:TRI). One block per row i.
__global__ __launch_bounds__(256) void k_x0bn(
    const float* __restrict__ x, const float* __restrict__ gam,
    const float* __restrict__ bet, u16* __restrict__ z) {
  int i = blockIdx.x;                             // 0..359
  int off = i * FN - (i * (i - 1)) / 2;
  for (int j = i + (int)threadIdx.x; j < FN; j += 256) {
    float s = 0.f, ss = 0.f;
    for (int b = 0; b < NG; b++) {
      float v = x[(size_t)(b * FN + i) * FN + j];
      s += v; ss += v * v;
    }
    float mean = s * (1.0f / NG);
    float var = fmaxf(ss * (1.0f / NG) - mean * mean, 0.f);
    float rstd = rsqrtf(var + EPS);
    int f = off + (j - i);
    float ga = gam[f] * rstd;
    float bb = bet[f] - mean * ga;
    for (int b = 0; b < NG; b++) {
      float v = x[(size_t)(b * FN + i) * FN + j];
      z[(size_t)b * ZLD + f] = f2bf(v * ga + bb);
    }
  }
}

__global__ void k_bnrelu(const float* __restrict__ y, const float* __restrict__ gam,
                         const float* __restrict__ bet, u16* __restrict__ a, int N) {
  int c = blockIdx.x * 256 + threadIdx.x;
  if (c >= N) return;
  float s = 0.f, ss = 0.f;
  for (int m = 0; m < NG; m++) { float v = y[(size_t)m * N + c]; s += v; ss += v * v; }
  float mean = s * (1.0f / NG);
  float var = fmaxf(ss * (1.0f / NG) - mean * mean, 0.f);
  float rstd = rsqrtf(var + EPS);
  float ga = gam[c] * rstd;
  float bb = bet[c] - mean * ga;
  for (int m = 0; m < NG; m++) {
    float v = y[(size_t)m * N + c] * ga + bb;
    a[(size_t)m * N + c] = f2bf(fmaxf(v, 0.f));
  }
}

// small MLP layer: y[m][n] = sum_k a[m][k]*W[k][n] + b[n]; a bf16, W f32
__global__ void k_mlp(const u16* __restrict__ a, const float* __restrict__ W,
                      const float* __restrict__ b, float* __restrict__ y, int K, int N) {
  int n = blockIdx.x * 256 + threadIdx.x;
  int m = blockIdx.y;
  if (n >= N) return;
  float acc = 0.f;
  for (int k = 0; k < K; k++)
    acc += bf2f(a[(size_t)m * K + k]) * W[(size_t)k * N + n];
  y[(size_t)m * N + n] = acc + b[n];
}

__global__ void k_head(const u16* __restrict__ a3, const float* __restrict__ W4,
                       const float* __restrict__ b4, float* __restrict__ out) {
  int m = threadIdx.x;                            // block 128
  float a0 = b4[0], a1 = b4[1];
  for (int k = 0; k < H2; k++) {
    float v = bf2f(a3[(size_t)m * H2 + k]);
    a0 += v * W4[k * 2];
    a1 += v * W4[k * 2 + 1];
  }
  float mx = fmaxf(a0, a1);
  float lse = mx + logf(expf(a0 - mx) + expf(a1 - mx));
  out[m * 2]     = a0 - lse;
  out[m * 2 + 1] = a1 - lse;
}

// ---------------- launch ----------------
extern "C" void kernel_launch(void* const* d_in, const int* in_sizes, int n_in,
                              void* d_out, int out_size, void* d_ws, size_t ws_size,
                              hipStream_t stream) {
  const float* x    = (const float*)d_in[0];
  const int* esrc   = (const int*)d_in[1];
  const int* edst   = (const int*)d_in[2];
  // d_in[3] = batch (uniform 360 nodes/graph; unused)
  const float* Wc1 = (const float*)d_in[4];  const float* bc1 = (const float*)d_in[5];
  const float* Wc2 = (const float*)d_in[6];  const float* bc2 = (const float*)d_in[7];
  const float* Wc3 = (const float*)d_in[8];  const float* bc3 = (const float*)d_in[9];
  const float* bn_g = (const float*)d_in[10]; const float* bn_b = (const float*)d_in[11];
  const float* bnh_g = (const float*)d_in[12]; const float* bnh_b = (const float*)d_in[13];
  const float* W1 = (const float*)d_in[14]; const float* b1 = (const float*)d_in[15];
  const float* g1 = (const float*)d_in[16]; const float* be1 = (const float*)d_in[17];
  const float* W2 = (const float*)d_in[18]; const float* b2 = (const float*)d_in[19];
  const float* g2 = (const float*)d_in[20]; const float* be2 = (const float*)d_in[21];
  const float* W3 = (const float*)d_in[22]; const float* b3 = (const float*)d_in[23];
  const float* g3 = (const float*)d_in[24]; const float* be3 = (const float*)d_in[25];
  const float* W4 = (const float*)d_in[26]; const float* b4 = (const float*)d_in[27];

  char* ws = (char*)d_ws;
  float* A32  = (float*)(ws + A32_OFF);
  u16*   Ab   = (u16*)(ws + AB_OFF);
  float* dinv = (float*)(ws + DEG_OFF);
  u16*   P    = (u16*)(ws + P_OFF);
  u16*   hA   = (u16*)(ws + HA_OFF);
  u16*   hB   = (u16*)(ws + HB_OFF);
  float* hp   = (float*)(ws + HP_OFF);
  u16*   z    = (u16*)(ws + Z_OFF);
  float* y1   = (float*)(ws + Y1_OFF);
  u16*   a1   = (u16*)(ws + A1_OFF);
  float* y2   = (float*)(ws + Y2_OFF);
  u16*   a2   = (u16*)(ws + A2_OFF);
  float* y3   = (float*)(ws + Y3_OFF);
  u16*   a3   = (u16*)(ws + A3_OFF);
  float* part = (float*)(ws + PART_OFF);

  // zero accumulators (ws is poisoned 0xAA before every call)
  (void)hipMemsetAsync(dinv, 0, (size_t)NN * 4, stream);
  (void)hipMemsetAsync(A32, 0, (size_t)NG * FN * FN * 4, stream);

  dim3 b256(256);
  // graph structure
  k_deg<<<dim3((NE + 255) / 256), b256, 0, stream>>>(edst, dinv);
  k_dinv<<<dim3((NN + 255) / 256), b256, 0, stream>>>(dinv);
  k_abuild<<<dim3((NE + 255) / 256), b256, 0, stream>>>(esrc, edst, dinv, A32);
  k_aconv<<<dim3(NG * FN * FN / 256), b256, 0, stream>>>(A32, Ab, dinv);

  // z lives in region0 which aliases A32 — issue its clear after k_aconv.
  (void)hipMemsetAsync(z, 0, (size_t)NG * ZLD * 2, stream);

  // GCN layer 1 (x is f32)
  k_gemm_xw_f32<<<dim3(NN / 64), b256, 0, stream>>>(x, Wc1, P, FN);
  k_gemm_agg<<<dim3(2, 6, NG), b256, 0, stream>>>(Ab, P, bc1, hA);
  k_pool<<<dim3(NG), dim3(128), 0, stream>>>(hA, hp, 0);
  // GCN layer 2
  k_gemm_xw_bf16<<<dim3(NN / 64), b256, 0, stream>>>(hA, Wc2, P, CH);
  k_gemm_agg<<<dim3(2, 6, NG), b256, 0, stream>>>(Ab, P, bc2, hB);
  k_pool<<<dim3(NG), dim3(128), 0, stream>>>(hB, hp, 1);
  // GCN layer 3
  k_gemm_xw_bf16<<<dim3(NN / 64), b256, 0, stream>>>(hB, Wc3, P, CH);
  k_gemm_agg<<<dim3(2, 6, NG), b256, 0, stream>>>(Ab, P, bc3, hA);
  k_pool<<<dim3(NG), dim3(128), 0, stream>>>(hA, hp, 2);

  // feature assembly: z = [BN(triu(x)) | BN(pooled h)]
  k_x0bn<<<dim3(FN), b256, 0, stream>>>(x, bn_g, bn_b, z);
  k_hbn<<<dim3(1), dim3(384), 0, stream>>>(hp, bnh_g, bnh_b, z);

  // MLP head
  k_gemm_big<<<dim3(2, 8, 32), b256, 0, stream>>>(z, W1, part);
  k_red<<<dim3(65536 / 256), b256, 0, stream>>>(part, b1, y1);
  k_bnrelu<<<dim3(2), b256, 0, stream>>>(y1, g1, be1, a1, H1);
  k_mlp<<<dim3(1, NG), b256, 0, stream>>>(a1, W2, b2, y2, H1, H2);
  k_bnrelu<<<dim3(1), b256, 0, stream>>>(y2, g2, be2, a2, H2);
  k_mlp<<<dim3(1, NG), b256, 0, stream>>>(a2, W3, b3, y3, H2, H2);
  k_bnrelu<<<dim3(1), b256, 0, stream>>>(y3, g3, be3, a3, H2);
  k_head<<<dim3(1), dim3(128), 0, stream>>>(a3, W4, b4, (float*)d_out);
}

// Round 4
// 1041.526 us; speedup vs baseline: 1.4045x; 1.4045x over previous
//
#include <hip/hip_runtime.h>
#include <hip/hip_bf16.h>
#include <math.h>

// ---------------- problem constants ----------------
#define FN 360            // nodes per graph == features
#define NG 128            // graphs
#define NN 46080          // NG*FN
#define CH 128            // hidden channels
#define NE 1000000        // edges
#define TRI 64980         // FN*(FN+1)/2
#define D1 65364          // TRI + 3*CH
#define ZLD 65376         // D1 padded to multiple of 32 (zeroed tail)
#define H1 512
#define H2 256
#define EPS 1e-5f
#define NSPLIT 128        // split-K for the big GEMM (chunk = 512)

typedef unsigned short u16;
typedef __attribute__((ext_vector_type(8))) short bf16x8;
typedef __attribute__((ext_vector_type(4))) float f32x4;

__device__ __forceinline__ float bf2f(u16 v) {
  union { unsigned u; float f; } x; x.u = ((unsigned)v) << 16; return x.f;
}
__device__ __forceinline__ u16 f2bf(float f) {
  union { float f; unsigned u; } x; x.f = f;
  unsigned r = x.u + 0x7fffu + ((x.u >> 16) & 1u);   // RNE
  return (u16)(r >> 16);
}
__device__ __forceinline__ bf16x8 bzero8() {
  bf16x8 z;
#pragma unroll
  for (int j = 0; j < 8; j++) z[j] = 0;
  return z;
}

// ---------------- workspace layout (bytes) ----------------
static const size_t A32_OFF = 0;                       // f32 [NG*FN*FN]  (66,355,200)
static const size_t AB_OFF  = 66355200;                // bf16 [NG*FN*FN] (33,177,600)
static const size_t DEG_OFF = 99532800;                // f32 [NN]
static const size_t P_OFF   = 99717120;                // bf16 [NN*CH]  (PT: channel-major per graph)
static const size_t HA_OFF  = 111513600;               // bf16 [NN*CH]
static const size_t HB_OFF  = 123310080;               // bf16 [NN*CH]
static const size_t HP_OFF  = 135106560;               // f32 [NG*384]  -> ends 135,303,168
// region0 reuse (after k_aconv consumes A32):
static const size_t Z_OFF   = 0;                       // bf16 [NG*ZLD] (16,736,256)
static const size_t Y1_OFF  = 16736256;                // f32 [NG*H1]
static const size_t A1_OFF  = Y1_OFF + 262144;         // bf16 [NG*H1]
static const size_t Y2_OFF  = A1_OFF + 131072;         // f32 [NG*H2]
static const size_t A2_OFF  = Y2_OFF + 131072;         // bf16 [NG*H2]
static const size_t Y3_OFF  = A2_OFF + 65536;          // f32 [NG*H2]
static const size_t A3_OFF  = Y3_OFF + 131072;         // bf16 [NG*H2]
static const size_t PART_OFF= A3_OFF + 65536;          // f32 [NSPLIT*NG*H1] = 33.5 MB -> ends ~51.1 MB < 66.3 MB

// ---------------- graph-structure kernels ----------------
__global__ void k_deg(const int* __restrict__ dst, float* __restrict__ deg) {
  int e = blockIdx.x * 256 + threadIdx.x;
  if (e < NE) atomicAdd(&deg[dst[e]], 1.0f);
}

__global__ void k_dinv(float* __restrict__ deg) {
  int i = blockIdx.x * 256 + threadIdx.x;
  if (i < NN) deg[i] = rsqrtf(deg[i] + 1.0f);   // +1: self loop
}

__global__ void k_abuild(const int* __restrict__ src, const int* __restrict__ dst,
                         const float* __restrict__ dinv, float* __restrict__ A) {
  int e = blockIdx.x * 256 + threadIdx.x;
  if (e >= NE) return;
  int s = src[e], d = dst[e];
  int g = d / FN;
  int ls = s - g * FN, ld = d - g * FN;
  atomicAdd(&A[(size_t)g * FN * FN + (size_t)ld * FN + ls], dinv[s] * dinv[d]);
}

// fuse self-loop diagonal into the f32->bf16 conversion
__global__ void k_aconv(const float* __restrict__ A, u16* __restrict__ Ab,
                        const float* __restrict__ dinv) {
  int idx = blockIdx.x * 256 + threadIdx.x;   // < NG*FN*FN
  float v = A[idx];
  int rc = idx % (FN * FN);
  int r = rc / FN, c = rc % FN;
  if (r == c) {
    int g = idx / (FN * FN);
    float dv = dinv[g * FN + r];
    v += dv * dv;
  }
  Ab[idx] = f2bf(v);
}

// ------- MFMA GEMM (f32 A): PT = (X[M][K] @ W[K][128])^T per graph -------
// Block 256 = 4 waves; BM=64, BN=128; per-wave 32x64. K%8==0.
// W tile staged through LDS transposed (bf16) so B-frags are ds_read_b128.
// Output PT is channel-major per graph: PT[(g*CH + c)*FN + local_row].
__global__ __launch_bounds__(256) void k_gemm_xw_f32(
    const float* __restrict__ X, const float* __restrict__ W,
    u16* __restrict__ PT, int K) {
  __shared__ u16 WT[128][40];                 // [n][k] padded: row 80 B, 16B-aligned
  int wid = threadIdx.x >> 6, lane = threadIdx.x & 63;
  int quad = lane >> 4, l16 = lane & 15;
  int m0 = blockIdx.x * 64 + (wid & 1) * 32;
  int n0w = (wid >> 1) * 64;
  int kl = threadIdx.x >> 3, nseg = (threadIdx.x & 7) * 16;
  f32x4 acc[2][4];
#pragma unroll
  for (int i = 0; i < 2; i++)
#pragma unroll
    for (int j = 0; j < 4; j++) acc[i][j] = (f32x4){0,0,0,0};
  for (int k0 = 0; k0 < K; k0 += 32) {
    __syncthreads();
    int kg = k0 + kl;
    if (kg < K) {
      const float* wrow = W + (size_t)kg * CH + nseg;
      f32x4 w0 = *(const f32x4*)(wrow);
      f32x4 w1 = *(const f32x4*)(wrow + 4);
      f32x4 w2 = *(const f32x4*)(wrow + 8);
      f32x4 w3 = *(const f32x4*)(wrow + 12);
#pragma unroll
      for (int j = 0; j < 4; j++) {
        WT[nseg + j][kl]      = f2bf(w0[j]);
        WT[nseg + 4 + j][kl]  = f2bf(w1[j]);
        WT[nseg + 8 + j][kl]  = f2bf(w2[j]);
        WT[nseg + 12 + j][kl] = f2bf(w3[j]);
      }
    } else {
#pragma unroll
      for (int j = 0; j < 16; j++) WT[nseg + j][kl] = 0;
    }
    __syncthreads();
    int kk = k0 + quad * 8;
    bool kin = kk < K;
    bf16x8 af[2];
#pragma unroll
    for (int tm = 0; tm < 2; tm++) {
      int row = m0 + tm * 16 + l16;
      bf16x8 a = bzero8();
      if (kin) {
        f32x4 va = *(const f32x4*)(X + (size_t)row * K + kk);
        f32x4 vb = *(const f32x4*)(X + (size_t)row * K + kk + 4);
#pragma unroll
        for (int j = 0; j < 4; j++) { a[j] = (short)f2bf(va[j]); a[4 + j] = (short)f2bf(vb[j]); }
      }
      af[tm] = a;
    }
    bf16x8 bfr[4];
#pragma unroll
    for (int tn = 0; tn < 4; tn++)
      bfr[tn] = *(const bf16x8*)&WT[n0w + tn * 16 + l16][quad * 8];  // OOB-k rows are zeros
#pragma unroll
    for (int tm = 0; tm < 2; tm++)
#pragma unroll
      for (int tn = 0; tn < 4; tn++)
        acc[tm][tn] = __builtin_amdgcn_mfma_f32_16x16x32_bf16(af[tm], bfr[tn], acc[tm][tn], 0, 0, 0);
  }
#pragma unroll
  for (int tm = 0; tm < 2; tm++)
#pragma unroll
    for (int tn = 0; tn < 4; tn++) {
      int col = n0w + tn * 16 + l16;
      int rowb = m0 + tm * 16 + quad * 4;
#pragma unroll
      for (int r = 0; r < 4; r++) {
        int row = rowb + r;
        int g = row / FN, lr = row - g * FN;
        PT[((size_t)g * CH + col) * FN + lr] = f2bf(acc[tm][tn][r]);
      }
    }
}

// ------- MFMA GEMM (bf16 A [M][128]): PT = (X @ W)^T per graph, W f32 -------
__global__ __launch_bounds__(256) void k_gemm_xw_bf16(
    const u16* __restrict__ X, const float* __restrict__ W,
    u16* __restrict__ PT) {
  __shared__ u16 WT[128][40];
  int wid = threadIdx.x >> 6, lane = threadIdx.x & 63;
  int quad = lane >> 4, l16 = lane & 15;
  int m0 = blockIdx.x * 64 + (wid & 1) * 32;
  int n0w = (wid >> 1) * 64;
  int kl = threadIdx.x >> 3, nseg = (threadIdx.x & 7) * 16;
  f32x4 acc[2][4];
#pragma unroll
  for (int i = 0; i < 2; i++)
#pragma unroll
    for (int j = 0; j < 4; j++) acc[i][j] = (f32x4){0,0,0,0};
  for (int k0 = 0; k0 < CH; k0 += 32) {       // K = CH = 128, exact
    __syncthreads();
    int kg = k0 + kl;
    const float* wrow = W + (size_t)kg * CH + nseg;
    f32x4 w0 = *(const f32x4*)(wrow);
    f32x4 w1 = *(const f32x4*)(wrow + 4);
    f32x4 w2 = *(const f32x4*)(wrow + 8);
    f32x4 w3 = *(const f32x4*)(wrow + 12);
#pragma unroll
    for (int j = 0; j < 4; j++) {
      WT[nseg + j][kl]      = f2bf(w0[j]);
      WT[nseg + 4 + j][kl]  = f2bf(w1[j]);
      WT[nseg + 8 + j][kl]  = f2bf(w2[j]);
      WT[nseg + 12 + j][kl] = f2bf(w3[j]);
    }
    __syncthreads();
    int kk = k0 + quad * 8;
    bf16x8 af[2];
#pragma unroll
    for (int tm = 0; tm < 2; tm++) {
      int row = m0 + tm * 16 + l16;
      af[tm] = *(const bf16x8*)(X + (size_t)row * CH + kk);
    }
    bf16x8 bfr[4];
#pragma unroll
    for (int tn = 0; tn < 4; tn++)
      bfr[tn] = *(const bf16x8*)&WT[n0w + tn * 16 + l16][quad * 8];
#pragma unroll
    for (int tm = 0; tm < 2; tm++)
#pragma unroll
      for (int tn = 0; tn < 4; tn++)
        acc[tm][tn] = __builtin_amdgcn_mfma_f32_16x16x32_bf16(af[tm], bfr[tn], acc[tm][tn], 0, 0, 0);
  }
#pragma unroll
  for (int tm = 0; tm < 2; tm++)
#pragma unroll
    for (int tn = 0; tn < 4; tn++) {
      int col = n0w + tn * 16 + l16;
      int rowb = m0 + tm * 16 + quad * 4;
#pragma unroll
      for (int r = 0; r < 4; r++) {
        int row = rowb + r;
        int g = row / FN, lr = row - g * FN;
        PT[((size_t)g * CH + col) * FN + lr] = f2bf(acc[tm][tn][r]);
      }
    }
}

// ------- batched aggregation: H_g = tanh(A_g[360x360] @ P_g[360x128] + bias) -------
// P is channel-major (PT), so B-frags are contiguous bf16x8 along k.
__global__ __launch_bounds__(256) void k_gemm_agg(
    const u16* __restrict__ Ab, const u16* __restrict__ PT,
    const float* __restrict__ bias, u16* __restrict__ Hout) {
  int g = blockIdx.z;
  int wid = threadIdx.x >> 6, lane = threadIdx.x & 63;
  int quad = lane >> 4, l16 = lane & 15;
  int m0 = blockIdx.y * 64 + (wid & 1) * 32;
  int n0 = blockIdx.x * 64 + (wid >> 1) * 32;
  const u16* Ag = Ab + (size_t)g * FN * FN;
  const u16* PTg = PT + (size_t)g * CH * FN;
  f32x4 acc[2][2];
#pragma unroll
  for (int i = 0; i < 2; i++)
#pragma unroll
    for (int j = 0; j < 2; j++) acc[i][j] = (f32x4){0,0,0,0};
  for (int k0 = 0; k0 < FN; k0 += 32) {
    int kk = k0 + quad * 8;
    bool kin = kk < FN;                      // kk%8==0 and FN%8==0 -> full vector in-bounds
    bf16x8 af[2];
#pragma unroll
    for (int tm = 0; tm < 2; tm++) {
      int row = m0 + tm * 16 + l16;
      af[tm] = (kin && row < FN) ? *(const bf16x8*)(Ag + (size_t)row * FN + kk) : bzero8();
    }
    bf16x8 bfr[2];
#pragma unroll
    for (int tn = 0; tn < 2; tn++) {
      int col = n0 + tn * 16 + l16;
      bfr[tn] = kin ? *(const bf16x8*)(PTg + (size_t)col * FN + kk) : bzero8();
    }
#pragma unroll
    for (int tm = 0; tm < 2; tm++)
#pragma unroll
      for (int tn = 0; tn < 2; tn++)
        acc[tm][tn] = __builtin_amdgcn_mfma_f32_16x16x32_bf16(af[tm], bfr[tn], acc[tm][tn], 0, 0, 0);
  }
#pragma unroll
  for (int tm = 0; tm < 2; tm++)
#pragma unroll
    for (int tn = 0; tn < 2; tn++) {
      int col = n0 + tn * 16 + l16;
      float bc = bias[col];
      int rowb = m0 + tm * 16 + quad * 4;
#pragma unroll
      for (int r = 0; r < 4; r++) {
        int row = rowb + r;
        if (row < FN)
          Hout[(size_t)(g * FN + row) * CH + col] = f2bf(tanhf(acc[tm][tn][r] + bc));
      }
    }
}

// ------- big GEMM: part[s] = Z[128][chunk] @ W1[chunk][512] (W1 f32, LDS-staged) -------
// grid (4 n-blocks, NSPLIT); block 256 = 4 waves; BM=128, BN=128; wave: 32m x 128n.
__global__ __launch_bounds__(256) void k_gemm_big(
    const u16* __restrict__ Z, const float* __restrict__ W1f, float* __restrict__ part) {
  __shared__ u16 WT[128][40];
  int s = blockIdx.y;
  int n0b = blockIdx.x * 128;
  int wid = threadIdx.x >> 6, lane = threadIdx.x & 63;
  int quad = lane >> 4, l16 = lane & 15;
  int m0 = wid * 32;
  int kl = threadIdx.x >> 3, nseg = (threadIdx.x & 7) * 16;
  int kbeg = s * 512;
  int kend = (ZLD < kbeg + 512) ? ZLD : (kbeg + 512);
  f32x4 acc[2][8];
#pragma unroll
  for (int i = 0; i < 2; i++)
#pragma unroll
    for (int j = 0; j < 8; j++) acc[i][j] = (f32x4){0,0,0,0};
  for (int k0 = kbeg; k0 < kend; k0 += 32) {
    __syncthreads();
    int kg = k0 + kl;
    if (kg < D1) {
      const float* wrow = W1f + (size_t)kg * H1 + n0b + nseg;
      f32x4 w0 = *(const f32x4*)(wrow);
      f32x4 w1 = *(const f32x4*)(wrow + 4);
      f32x4 w2 = *(const f32x4*)(wrow + 8);
      f32x4 w3 = *(const f32x4*)(wrow + 12);
#pragma unroll
      for (int j = 0; j < 4; j++) {
        WT[nseg + j][kl]      = f2bf(w0[j]);
        WT[nseg + 4 + j][kl]  = f2bf(w1[j]);
        WT[nseg + 8 + j][kl]  = f2bf(w2[j]);
        WT[nseg + 12 + j][kl] = f2bf(w3[j]);
      }
    } else {
#pragma unroll
      for (int j = 0; j < 16; j++) WT[nseg + j][kl] = 0;
    }
    __syncthreads();
    int kk = k0 + quad * 8;                 // < ZLD always; Z tail is zeroed
    bf16x8 af[2];
#pragma unroll
    for (int tm = 0; tm < 2; tm++) {
      int row = m0 + tm * 16 + l16;         // < 128
      af[tm] = *(const bf16x8*)(Z + (size_t)row * ZLD + kk);
    }
    bf16x8 bfr[8];
#pragma unroll
    for (int tn = 0; tn < 8; tn++)
      bfr[tn] = *(const bf16x8*)&WT[tn * 16 + l16][quad * 8];
#pragma unroll
    for (int tm = 0; tm < 2; tm++)
#pragma unroll
      for (int tn = 0; tn < 8; tn++)
        acc[tm][tn] = __builtin_amdgcn_mfma_f32_16x16x32_bf16(af[tm], bfr[tn], acc[tm][tn], 0, 0, 0);
  }
#pragma unroll
  for (int tm = 0; tm < 2; tm++)
#pragma unroll
    for (int tn = 0; tn < 8; tn++) {
      int col = n0b + tn * 16 + l16;
      int rowb = m0 + tm * 16 + quad * 4;
#pragma unroll
      for (int r = 0; r < 4; r++)
        part[((size_t)s * NG + rowb + r) * H1 + col] = acc[tm][tn][r];
    }
}

__global__ void k_red(const float* __restrict__ part, const float* __restrict__ b1,
                      float* __restrict__ y1) {
  int idx = blockIdx.x * 256 + threadIdx.x;       // < 65536
  float s = 0.f;
#pragma unroll 8
  for (int i = 0; i < NSPLIT; i++) s += part[(size_t)i * 65536 + idx];
  y1[idx] = s + b1[idx & (H1 - 1)];
}

// ---------------- pooling / batch-norm kernels ----------------
__global__ void k_pool(const u16* __restrict__ h, float* __restrict__ hp, int layer) {
  int g = blockIdx.x, c = threadIdx.x;            // block 128
  float s = 0.f;
  for (int r = 0; r < FN; r++) s += bf2f(h[(size_t)(g * FN + r) * CH + c]);
  hp[g * 384 + layer * CH + c] = s * (1.0f / FN);
}

__global__ void k_hbn(const float* __restrict__ hp, const float* __restrict__ gam,
                      const float* __restrict__ bet, u16* __restrict__ z) {
  int c = threadIdx.x;                            // block 384
  float s = 0.f, ss = 0.f;
  for (int m = 0; m < NG; m++) { float v = hp[m * 384 + c]; s += v; ss += v * v; }
  float mean = s * (1.0f / NG);
  float var = fmaxf(ss * (1.0f / NG) - mean * mean, 0.f);
  float rstd = rsqrtf(var + EPS);
  float ga = gam[c] * rstd;
  float bb = bet[c] - mean * ga;
  for (int m = 0; m < NG; m++)
    z[(size_t)m * ZLD + TRI + c] = f2bf(hp[m * 384 + c] * ga + bb);
}

// triu gather + BN of raw connectome -> z[:, 0:TRI). One block per row i.
__global__ __launch_bounds__(256) void k_x0bn(
    const float* __restrict__ x, const float* __restrict__ gam,
    const float* __restrict__ bet, u16* __restrict__ z) {
  int i = blockIdx.x;                             // 0..359
  int off = i * FN - (i * (i - 1)) / 2;
  for (int j = i + (int)threadIdx.x; j < FN; j += 256) {
    float s = 0.f, ss = 0.f;
    for (int b = 0; b < NG; b++) {
      float v = x[(size_t)(b * FN + i) * FN + j];
      s += v; ss += v * v;
    }
    float mean = s * (1.0f / NG);
    float var = fmaxf(ss * (1.0f / NG) - mean * mean, 0.f);
    float rstd = rsqrtf(var + EPS);
    int f = off + (j - i);
    float ga = gam[f] * rstd;
    float bb = bet[f] - mean * ga;
    for (int b = 0; b < NG; b++) {
      float v = x[(size_t)(b * FN + i) * FN + j];
      z[(size_t)b * ZLD + f] = f2bf(v * ga + bb);
    }
  }
}

__global__ void k_bnrelu(const float* __restrict__ y, const float* __restrict__ gam,
                         const float* __restrict__ bet, u16* __restrict__ a, int N) {
  int c = blockIdx.x * 256 + threadIdx.x;
  if (c >= N) return;
  float s = 0.f, ss = 0.f;
  for (int m = 0; m < NG; m++) { float v = y[(size_t)m * N + c]; s += v; ss += v * v; }
  float mean = s * (1.0f / NG);
  float var = fmaxf(ss * (1.0f / NG) - mean * mean, 0.f);
  float rstd = rsqrtf(var + EPS);
  float ga = gam[c] * rstd;
  float bb = bet[c] - mean * ga;
  for (int m = 0; m < NG; m++) {
    float v = y[(size_t)m * N + c] * ga + bb;
    a[(size_t)m * N + c] = f2bf(fmaxf(v, 0.f));
  }
}

// small MLP layer: y[m][n] = sum_k a[m][k]*W[k][n] + b[n]; a bf16, W f32
__global__ void k_mlp(const u16* __restrict__ a, const float* __restrict__ W,
                      const float* __restrict__ b, float* __restrict__ y, int K, int N) {
  int n = blockIdx.x * 256 + threadIdx.x;
  int m = blockIdx.y;
  if (n >= N) return;
  float acc = 0.f;
  for (int k = 0; k < K; k++)
    acc += bf2f(a[(size_t)m * K + k]) * W[(size_t)k * N + n];
  y[(size_t)m * N + n] = acc + b[n];
}

__global__ void k_head(const u16* __restrict__ a3, const float* __restrict__ W4,
                       const float* __restrict__ b4, float* __restrict__ out) {
  int m = threadIdx.x;                            // block 128
  float a0 = b4[0], a1 = b4[1];
  for (int k = 0; k < H2; k++) {
    float v = bf2f(a3[(size_t)m * H2 + k]);
    a0 += v * W4[k * 2];
    a1 += v * W4[k * 2 + 1];
  }
  float mx = fmaxf(a0, a1);
  float lse = mx + logf(expf(a0 - mx) + expf(a1 - mx));
  out[m * 2]     = a0 - lse;
  out[m * 2 + 1] = a1 - lse;
}

// ---------------- launch ----------------
extern "C" void kernel_launch(void* const* d_in, const int* in_sizes, int n_in,
                              void* d_out, int out_size, void* d_ws, size_t ws_size,
                              hipStream_t stream) {
  const float* x    = (const float*)d_in[0];
  const int* esrc   = (const int*)d_in[1];
  const int* edst   = (const int*)d_in[2];
  // d_in[3] = batch (uniform 360 nodes/graph; unused)
  const float* Wc1 = (const float*)d_in[4];  const float* bc1 = (const float*)d_in[5];
  const float* Wc2 = (const float*)d_in[6];  const float* bc2 = (const float*)d_in[7];
  const float* Wc3 = (const float*)d_in[8];  const float* bc3 = (const float*)d_in[9];
  const float* bn_g = (const float*)d_in[10]; const float* bn_b = (const float*)d_in[11];
  const float* bnh_g = (const float*)d_in[12]; const float* bnh_b = (const float*)d_in[13];
  const float* W1 = (const float*)d_in[14]; const float* b1 = (const float*)d_in[15];
  const float* g1 = (const float*)d_in[16]; const float* be1 = (const float*)d_in[17];
  const float* W2 = (const float*)d_in[18]; const float* b2 = (const float*)d_in[19];
  const float* g2 = (const float*)d_in[20]; const float* be2 = (const float*)d_in[21];
  const float* W3 = (const float*)d_in[22]; const float* b3 = (const float*)d_in[23];
  const float* g3 = (const float*)d_in[24]; const float* be3 = (const float*)d_in[25];
  const float* W4 = (const float*)d_in[26]; const float* b4 = (const float*)d_in[27];

  char* ws = (char*)d_ws;
  float* A32  = (float*)(ws + A32_OFF);
  u16*   Ab   = (u16*)(ws + AB_OFF);
  float* dinv = (float*)(ws + DEG_OFF);
  u16*   PT   = (u16*)(ws + P_OFF);
  u16*   hA   = (u16*)(ws + HA_OFF);
  u16*   hB   = (u16*)(ws + HB_OFF);
  float* hp   = (float*)(ws + HP_OFF);
  u16*   z    = (u16*)(ws + Z_OFF);
  float* y1   = (float*)(ws + Y1_OFF);
  u16*   a1   = (u16*)(ws + A1_OFF);
  float* y2   = (float*)(ws + Y2_OFF);
  u16*   a2   = (u16*)(ws + A2_OFF);
  float* y3   = (float*)(ws + Y3_OFF);
  u16*   a3   = (u16*)(ws + A3_OFF);
  float* part = (float*)(ws + PART_OFF);

  // zero accumulators (ws is poisoned 0xAA before every call)
  (void)hipMemsetAsync(dinv, 0, (size_t)NN * 4, stream);
  (void)hipMemsetAsync(A32, 0, (size_t)NG * FN * FN * 4, stream);

  dim3 b256(256);
  // graph structure
  k_deg<<<dim3((NE + 255) / 256), b256, 0, stream>>>(edst, dinv);
  k_dinv<<<dim3((NN + 255) / 256), b256, 0, stream>>>(dinv);
  k_abuild<<<dim3((NE + 255) / 256), b256, 0, stream>>>(esrc, edst, dinv, A32);
  k_aconv<<<dim3(NG * FN * FN / 256), b256, 0, stream>>>(A32, Ab, dinv);

  // z lives in region0 which aliases A32 — issue its clear after k_aconv.
  (void)hipMemsetAsync(z, 0, (size_t)NG * ZLD * 2, stream);

  // GCN layer 1 (x is f32)
  k_gemm_xw_f32<<<dim3(NN / 64), b256, 0, stream>>>(x, Wc1, PT, FN);
  k_gemm_agg<<<dim3(2, 6, NG), b256, 0, stream>>>(Ab, PT, bc1, hA);
  k_pool<<<dim3(NG), dim3(128), 0, stream>>>(hA, hp, 0);
  // GCN layer 2
  k_gemm_xw_bf16<<<dim3(NN / 64), b256, 0, stream>>>(hA, Wc2, PT);
  k_gemm_agg<<<dim3(2, 6, NG), b256, 0, stream>>>(Ab, PT, bc2, hB);
  k_pool<<<dim3(NG), dim3(128), 0, stream>>>(hB, hp, 1);
  // GCN layer 3
  k_gemm_xw_bf16<<<dim3(NN / 64), b256, 0, stream>>>(hB, Wc3, PT);
  k_gemm_agg<<<dim3(2, 6, NG), b256, 0, stream>>>(Ab, PT, bc3, hA);
  k_pool<<<dim3(NG), dim3(128), 0, stream>>>(hA, hp, 2);

  // feature assembly: z = [BN(triu(x)) | BN(pooled h)]
  k_x0bn<<<dim3(FN), b256, 0, stream>>>(x, bn_g, bn_b, z);
  k_hbn<<<dim3(1), dim3(384), 0, stream>>>(hp, bnh_g, bnh_b, z);

  // MLP head
  k_gemm_big<<<dim3(4, NSPLIT), b256, 0, stream>>>(z, W1, part);
  k_red<<<dim3(65536 / 256), b256, 0, stream>>>(part, b1, y1);
  k_bnrelu<<<dim3(2), b256, 0, stream>>>(y1, g1, be1, a1, H1);
  k_mlp<<<dim3(1, NG), b256, 0, stream>>>(a1, W2, b2, y2, H1, H2);
  k_bnrelu<<<dim3(1), b256, 0, stream>>>(y2, g2, be2, a2, H2);
  k_mlp<<<dim3(1, NG), b256, 0, stream>>>(a2, W3, b3, y3, H2, H2);
  k_bnrelu<<<dim3(1), b256, 0, stream>>>(y3, g3, be3, a3, H2);
  k_head<<<dim3(1), dim3(128), 0, stream>>>(a3, W4, b4, (float*)d_out);
}

// Round 5
// 778.807 us; speedup vs baseline: 1.8783x; 1.3373x over previous
//
#include <hip/hip_runtime.h>
#include <hip/hip_bf16.h>
#include <math.h>

// ---------------- problem constants ----------------
#define FN 360            // nodes per graph == features
#define NG 128            // graphs
#define NN 46080          // NG*FN
#define CH 128            // hidden channels
#define NE 1000000        // edges
#define TRI 64980         // FN*(FN+1)/2
#define D1 65364          // TRI + 3*CH
#define ZLD 65376         // D1 padded to multiple of 32 (zeroed tail)
#define H1 512
#define H2 256
#define EPS 1e-5f
#define NSPLIT 128        // split-K for the big GEMM (chunk = 512)

typedef unsigned short u16;
typedef __attribute__((ext_vector_type(8))) short bf16x8;
typedef __attribute__((ext_vector_type(4))) float f32x4;

__device__ __forceinline__ float bf2f(u16 v) {
  union { unsigned u; float f; } x; x.u = ((unsigned)v) << 16; return x.f;
}
__device__ __forceinline__ u16 f2bf(float f) {
  union { float f; unsigned u; } x; x.f = f;
  unsigned r = x.u + 0x7fffu + ((x.u >> 16) & 1u);   // RNE
  return (u16)(r >> 16);
}
__device__ __forceinline__ bf16x8 bzero8() {
  bf16x8 z;
#pragma unroll
  for (int j = 0; j < 8; j++) z[j] = 0;
  return z;
}

// ---------------- workspace layout (bytes) ----------------
static const size_t A32_OFF = 0;                       // f32 [NG*FN*FN]  (66,355,200)
static const size_t AB_OFF  = 66355200;                // bf16 [NG*FN*FN] (33,177,600)
static const size_t DEG_OFF = 99532800;                // f32 [NN]
static const size_t P_OFF   = 99717120;                // bf16 [NN*CH]  (PT: channel-major per graph)
static const size_t HA_OFF  = 111513600;               // bf16 [NN*CH]
static const size_t HB_OFF  = 123310080;               // bf16 [NN*CH]
static const size_t HP_OFF  = 135106560;               // f32 [NG*384]  -> ends 135,303,168
// region0 reuse (after k_aconv consumes A32):
static const size_t Z_OFF   = 0;                       // bf16 [NG*ZLD] (16,736,256)
static const size_t Y1_OFF  = 16736256;                // f32 [NG*H1]
static const size_t A1_OFF  = Y1_OFF + 262144;         // bf16 [NG*H1]
static const size_t Y2_OFF  = A1_OFF + 131072;         // f32 [NG*H2]
static const size_t A2_OFF  = Y2_OFF + 131072;         // bf16 [NG*H2]
static const size_t Y3_OFF  = A2_OFF + 65536;          // f32 [NG*H2]
static const size_t A3_OFF  = Y3_OFF + 131072;         // bf16 [NG*H2]
static const size_t PART_OFF= A3_OFF + 65536;          // f32 [NSPLIT*NG*H1] = 33.5 MB

// ---------------- graph-structure kernels ----------------
__global__ void k_deg(const int* __restrict__ dst, float* __restrict__ deg) {
  int e = blockIdx.x * 256 + threadIdx.x;
  if (e < NE) atomicAdd(&deg[dst[e]], 1.0f);
}

__global__ void k_dinv(float* __restrict__ deg) {
  int i = blockIdx.x * 256 + threadIdx.x;
  if (i < NN) deg[i] = rsqrtf(deg[i] + 1.0f);   // +1: self loop
}

__global__ void k_abuild(const int* __restrict__ src, const int* __restrict__ dst,
                         const float* __restrict__ dinv, float* __restrict__ A) {
  int e = blockIdx.x * 256 + threadIdx.x;
  if (e >= NE) return;
  int s = src[e], d = dst[e];
  int g = d / FN;
  int ls = s - g * FN, ld = d - g * FN;
  atomicAdd(&A[(size_t)g * FN * FN + (size_t)ld * FN + ls], dinv[s] * dinv[d]);
}

// fuse self-loop diagonal into the f32->bf16 conversion
__global__ void k_aconv(const float* __restrict__ A, u16* __restrict__ Ab,
                        const float* __restrict__ dinv) {
  int idx = blockIdx.x * 256 + threadIdx.x;   // < NG*FN*FN
  float v = A[idx];
  int rc = idx % (FN * FN);
  int r = rc / FN, c = rc % FN;
  if (r == c) {
    int g = idx / (FN * FN);
    float dv = dinv[g * FN + r];
    v += dv * dv;
  }
  Ab[idx] = f2bf(v);
}

// ------- MFMA GEMM (f32 A): PT = (X[M][K] @ W[K][128])^T per graph -------
__global__ __launch_bounds__(256) void k_gemm_xw_f32(
    const float* __restrict__ X, const float* __restrict__ W,
    u16* __restrict__ PT, int K) {
  __shared__ __attribute__((aligned(16))) u16 WT[128][40];
  int wid = threadIdx.x >> 6, lane = threadIdx.x & 63;
  int quad = lane >> 4, l16 = lane & 15;
  int m0 = blockIdx.x * 64 + (wid & 1) * 32;
  int n0w = (wid >> 1) * 64;
  int kl = threadIdx.x >> 3, nseg = (threadIdx.x & 7) * 16;
  f32x4 acc[2][4];
#pragma unroll
  for (int i = 0; i < 2; i++)
#pragma unroll
    for (int j = 0; j < 4; j++) acc[i][j] = (f32x4){0,0,0,0};
  for (int k0 = 0; k0 < K; k0 += 32) {
    __syncthreads();
    int kg = k0 + kl;
    if (kg < K) {
      const float* wrow = W + (size_t)kg * CH + nseg;
      f32x4 w0 = *(const f32x4*)(wrow);
      f32x4 w1 = *(const f32x4*)(wrow + 4);
      f32x4 w2 = *(const f32x4*)(wrow + 8);
      f32x4 w3 = *(const f32x4*)(wrow + 12);
#pragma unroll
      for (int j = 0; j < 4; j++) {
        WT[nseg + j][kl]      = f2bf(w0[j]);
        WT[nseg + 4 + j][kl]  = f2bf(w1[j]);
        WT[nseg + 8 + j][kl]  = f2bf(w2[j]);
        WT[nseg + 12 + j][kl] = f2bf(w3[j]);
      }
    } else {
#pragma unroll
      for (int j = 0; j < 16; j++) WT[nseg + j][kl] = 0;
    }
    __syncthreads();
    int kk = k0 + quad * 8;
    bool kin = kk < K;
    bf16x8 af[2];
#pragma unroll
    for (int tm = 0; tm < 2; tm++) {
      int row = m0 + tm * 16 + l16;
      bf16x8 a = bzero8();
      if (kin) {
        f32x4 va = *(const f32x4*)(X + (size_t)row * K + kk);
        f32x4 vb = *(const f32x4*)(X + (size_t)row * K + kk + 4);
#pragma unroll
        for (int j = 0; j < 4; j++) { a[j] = (short)f2bf(va[j]); a[4 + j] = (short)f2bf(vb[j]); }
      }
      af[tm] = a;
    }
    bf16x8 bfr[4];
#pragma unroll
    for (int tn = 0; tn < 4; tn++)
      bfr[tn] = *(const bf16x8*)&WT[n0w + tn * 16 + l16][quad * 8];
#pragma unroll
    for (int tm = 0; tm < 2; tm++)
#pragma unroll
      for (int tn = 0; tn < 4; tn++)
        acc[tm][tn] = __builtin_amdgcn_mfma_f32_16x16x32_bf16(af[tm], bfr[tn], acc[tm][tn], 0, 0, 0);
  }
#pragma unroll
  for (int tm = 0; tm < 2; tm++)
#pragma unroll
    for (int tn = 0; tn < 4; tn++) {
      int col = n0w + tn * 16 + l16;
      int rowb = m0 + tm * 16 + quad * 4;
#pragma unroll
      for (int r = 0; r < 4; r++) {
        int row = rowb + r;
        int g = row / FN, lr = row - g * FN;
        PT[((size_t)g * CH + col) * FN + lr] = f2bf(acc[tm][tn][r]);
      }
    }
}

// ------- MFMA GEMM (bf16 A [M][128]): PT = (X @ W)^T per graph, W f32 -------
__global__ __launch_bounds__(256) void k_gemm_xw_bf16(
    const u16* __restrict__ X, const float* __restrict__ W,
    u16* __restrict__ PT) {
  __shared__ __attribute__((aligned(16))) u16 WT[128][40];
  int wid = threadIdx.x >> 6, lane = threadIdx.x & 63;
  int quad = lane >> 4, l16 = lane & 15;
  int m0 = blockIdx.x * 64 + (wid & 1) * 32;
  int n0w = (wid >> 1) * 64;
  int kl = threadIdx.x >> 3, nseg = (threadIdx.x & 7) * 16;
  f32x4 acc[2][4];
#pragma unroll
  for (int i = 0; i < 2; i++)
#pragma unroll
    for (int j = 0; j < 4; j++) acc[i][j] = (f32x4){0,0,0,0};
  for (int k0 = 0; k0 < CH; k0 += 32) {
    __syncthreads();
    int kg = k0 + kl;
    const float* wrow = W + (size_t)kg * CH + nseg;
    f32x4 w0 = *(const f32x4*)(wrow);
    f32x4 w1 = *(const f32x4*)(wrow + 4);
    f32x4 w2 = *(const f32x4*)(wrow + 8);
    f32x4 w3 = *(const f32x4*)(wrow + 12);
#pragma unroll
    for (int j = 0; j < 4; j++) {
      WT[nseg + j][kl]      = f2bf(w0[j]);
      WT[nseg + 4 + j][kl]  = f2bf(w1[j]);
      WT[nseg + 8 + j][kl]  = f2bf(w2[j]);
      WT[nseg + 12 + j][kl] = f2bf(w3[j]);
    }
    __syncthreads();
    int kk = k0 + quad * 8;
    bf16x8 af[2];
#pragma unroll
    for (int tm = 0; tm < 2; tm++) {
      int row = m0 + tm * 16 + l16;
      af[tm] = *(const bf16x8*)(X + (size_t)row * CH + kk);
    }
    bf16x8 bfr[4];
#pragma unroll
    for (int tn = 0; tn < 4; tn++)
      bfr[tn] = *(const bf16x8*)&WT[n0w + tn * 16 + l16][quad * 8];
#pragma unroll
    for (int tm = 0; tm < 2; tm++)
#pragma unroll
      for (int tn = 0; tn < 4; tn++)
        acc[tm][tn] = __builtin_amdgcn_mfma_f32_16x16x32_bf16(af[tm], bfr[tn], acc[tm][tn], 0, 0, 0);
  }
#pragma unroll
  for (int tm = 0; tm < 2; tm++)
#pragma unroll
    for (int tn = 0; tn < 4; tn++) {
      int col = n0w + tn * 16 + l16;
      int rowb = m0 + tm * 16 + quad * 4;
#pragma unroll
      for (int r = 0; r < 4; r++) {
        int row = rowb + r;
        int g = row / FN, lr = row - g * FN;
        PT[((size_t)g * CH + col) * FN + lr] = f2bf(acc[tm][tn][r]);
      }
    }
}

// ------- batched aggregation: H_g = tanh(A_g @ P_g + bias), PT channel-major -------
__global__ __launch_bounds__(256) void k_gemm_agg(
    const u16* __restrict__ Ab, const u16* __restrict__ PT,
    const float* __restrict__ bias, u16* __restrict__ Hout) {
  int g = blockIdx.z;
  int wid = threadIdx.x >> 6, lane = threadIdx.x & 63;
  int quad = lane >> 4, l16 = lane & 15;
  int m0 = blockIdx.y * 64 + (wid & 1) * 32;
  int n0 = blockIdx.x * 64 + (wid >> 1) * 32;
  const u16* Ag = Ab + (size_t)g * FN * FN;
  const u16* PTg = PT + (size_t)g * CH * FN;
  f32x4 acc[2][2];
#pragma unroll
  for (int i = 0; i < 2; i++)
#pragma unroll
    for (int j = 0; j < 2; j++) acc[i][j] = (f32x4){0,0,0,0};
  for (int k0 = 0; k0 < FN; k0 += 32) {
    int kk = k0 + quad * 8;
    bool kin = kk < FN;
    bf16x8 af[2];
#pragma unroll
    for (int tm = 0; tm < 2; tm++) {
      int row = m0 + tm * 16 + l16;
      af[tm] = (kin && row < FN) ? *(const bf16x8*)(Ag + (size_t)row * FN + kk) : bzero8();
    }
    bf16x8 bfr[2];
#pragma unroll
    for (int tn = 0; tn < 2; tn++) {
      int col = n0 + tn * 16 + l16;
      bfr[tn] = kin ? *(const bf16x8*)(PTg + (size_t)col * FN + kk) : bzero8();
    }
#pragma unroll
    for (int tm = 0; tm < 2; tm++)
#pragma unroll
      for (int tn = 0; tn < 2; tn++)
        acc[tm][tn] = __builtin_amdgcn_mfma_f32_16x16x32_bf16(af[tm], bfr[tn], acc[tm][tn], 0, 0, 0);
  }
#pragma unroll
  for (int tm = 0; tm < 2; tm++)
#pragma unroll
    for (int tn = 0; tn < 2; tn++) {
      int col = n0 + tn * 16 + l16;
      float bc = bias[col];
      int rowb = m0 + tm * 16 + quad * 4;
#pragma unroll
      for (int r = 0; r < 4; r++) {
        int row = rowb + r;
        if (row < FN)
          Hout[(size_t)(g * FN + row) * CH + col] = f2bf(tanhf(acc[tm][tn][r] + bc));
      }
    }
}

// ------- big GEMM: part[s] = Z[128][chunk] @ W1[chunk][512] (LDS-staged) -------
__global__ __launch_bounds__(256) void k_gemm_big(
    const u16* __restrict__ Z, const float* __restrict__ W1f, float* __restrict__ part) {
  __shared__ __attribute__((aligned(16))) u16 WT[128][40];
  int s = blockIdx.y;
  int n0b = blockIdx.x * 128;
  int wid = threadIdx.x >> 6, lane = threadIdx.x & 63;
  int quad = lane >> 4, l16 = lane & 15;
  int m0 = wid * 32;
  int kl = threadIdx.x >> 3, nseg = (threadIdx.x & 7) * 16;
  int kbeg = s * 512;
  int kend = (ZLD < kbeg + 512) ? ZLD : (kbeg + 512);
  f32x4 acc[2][8];
#pragma unroll
  for (int i = 0; i < 2; i++)
#pragma unroll
    for (int j = 0; j < 8; j++) acc[i][j] = (f32x4){0,0,0,0};
  for (int k0 = kbeg; k0 < kend; k0 += 32) {
    __syncthreads();
    int kg = k0 + kl;
    if (kg < D1) {
      const float* wrow = W1f + (size_t)kg * H1 + n0b + nseg;
      f32x4 w0 = *(const f32x4*)(wrow);
      f32x4 w1 = *(const f32x4*)(wrow + 4);
      f32x4 w2 = *(const f32x4*)(wrow + 8);
      f32x4 w3 = *(const f32x4*)(wrow + 12);
#pragma unroll
      for (int j = 0; j < 4; j++) {
        WT[nseg + j][kl]      = f2bf(w0[j]);
        WT[nseg + 4 + j][kl]  = f2bf(w1[j]);
        WT[nseg + 8 + j][kl]  = f2bf(w2[j]);
        WT[nseg + 12 + j][kl] = f2bf(w3[j]);
      }
    } else {
#pragma unroll
      for (int j = 0; j < 16; j++) WT[nseg + j][kl] = 0;
    }
    __syncthreads();
    int kk = k0 + quad * 8;
    bf16x8 af[2];
#pragma unroll
    for (int tm = 0; tm < 2; tm++) {
      int row = m0 + tm * 16 + l16;
      af[tm] = *(const bf16x8*)(Z + (size_t)row * ZLD + kk);
    }
    bf16x8 bfr[8];
#pragma unroll
    for (int tn = 0; tn < 8; tn++)
      bfr[tn] = *(const bf16x8*)&WT[tn * 16 + l16][quad * 8];
#pragma unroll
    for (int tm = 0; tm < 2; tm++)
#pragma unroll
      for (int tn = 0; tn < 8; tn++)
        acc[tm][tn] = __builtin_amdgcn_mfma_f32_16x16x32_bf16(af[tm], bfr[tn], acc[tm][tn], 0, 0, 0);
  }
#pragma unroll
  for (int tm = 0; tm < 2; tm++)
#pragma unroll
    for (int tn = 0; tn < 8; tn++) {
      int col = n0b + tn * 16 + l16;
      int rowb = m0 + tm * 16 + quad * 4;
#pragma unroll
      for (int r = 0; r < 4; r++)
        part[((size_t)s * NG + rowb + r) * H1 + col] = acc[tm][tn][r];
    }
}

__global__ void k_red(const float* __restrict__ part, const float* __restrict__ b1,
                      float* __restrict__ y1) {
  int idx = blockIdx.x * 256 + threadIdx.x;       // < 65536
  float s = 0.f;
#pragma unroll 8
  for (int i = 0; i < NSPLIT; i++) s += part[(size_t)i * 65536 + idx];
  y1[idx] = s + b1[idx & (H1 - 1)];
}

// ------- small MLP GEMM: Y[128][N] = A[128][K](bf16) @ W[K][N](f32) + b -------
// grid (N/64); block 256 = 4 waves; wave handles 32 m-rows x 64 n.
__global__ __launch_bounds__(256) void k_mlp_gemm(
    const u16* __restrict__ A, const float* __restrict__ W,
    const float* __restrict__ bias, float* __restrict__ Y, int K, int N) {
  __shared__ __attribute__((aligned(16))) u16 WT[64][40];
  int wid = threadIdx.x >> 6, lane = threadIdx.x & 63;
  int quad = lane >> 4, l16 = lane & 15;
  int n0b = blockIdx.x * 64;
  int m0 = wid * 32;
  int kl = threadIdx.x >> 3;          // 0..31
  int nseg = (threadIdx.x & 7) * 8;   // 0..56
  f32x4 acc[2][4];
#pragma unroll
  for (int i = 0; i < 2; i++)
#pragma unroll
    for (int j = 0; j < 4; j++) acc[i][j] = (f32x4){0,0,0,0};
  for (int k0 = 0; k0 < K; k0 += 32) {     // K % 32 == 0
    __syncthreads();
    const float* wrow = W + (size_t)(k0 + kl) * N + n0b + nseg;
    f32x4 w0 = *(const f32x4*)(wrow);
    f32x4 w1 = *(const f32x4*)(wrow + 4);
#pragma unroll
    for (int j = 0; j < 4; j++) {
      WT[nseg + j][kl]     = f2bf(w0[j]);
      WT[nseg + 4 + j][kl] = f2bf(w1[j]);
    }
    __syncthreads();
    int kk = k0 + quad * 8;
    bf16x8 af[2];
#pragma unroll
    for (int tm = 0; tm < 2; tm++) {
      int row = m0 + tm * 16 + l16;        // < 128
      af[tm] = *(const bf16x8*)(A + (size_t)row * K + kk);
    }
    bf16x8 bfr[4];
#pragma unroll
    for (int tn = 0; tn < 4; tn++)
      bfr[tn] = *(const bf16x8*)&WT[tn * 16 + l16][quad * 8];
#pragma unroll
    for (int tm = 0; tm < 2; tm++)
#pragma unroll
      for (int tn = 0; tn < 4; tn++)
        acc[tm][tn] = __builtin_amdgcn_mfma_f32_16x16x32_bf16(af[tm], bfr[tn], acc[tm][tn], 0, 0, 0);
  }
#pragma unroll
  for (int tm = 0; tm < 2; tm++)
#pragma unroll
    for (int tn = 0; tn < 4; tn++) {
      int col = n0b + tn * 16 + l16;
      float bc = bias[col];
      int rowb = m0 + tm * 16 + quad * 4;
#pragma unroll
      for (int r = 0; r < 4; r++)
        Y[(size_t)(rowb + r) * N + col] = acc[tm][tn][r] + bc;
    }
}

// ---------------- pooling / batch-norm kernels ----------------
__global__ void k_pool(const u16* __restrict__ h, float* __restrict__ hp, int layer) {
  int g = blockIdx.x, c = threadIdx.x;            // block 128
  float s = 0.f;
#pragma unroll 8
  for (int r = 0; r < FN; r++) s += bf2f(h[(size_t)(g * FN + r) * CH + c]);
  hp[g * 384 + layer * CH + c] = s * (1.0f / FN);
}

__global__ void k_hbn(const float* __restrict__ hp, const float* __restrict__ gam,
                      const float* __restrict__ bet, u16* __restrict__ z) {
  int c = threadIdx.x;                            // block 384
  float s = 0.f, ss = 0.f;
#pragma unroll 8
  for (int m = 0; m < NG; m++) { float v = hp[m * 384 + c]; s += v; ss += v * v; }
  float mean = s * (1.0f / NG);
  float var = fmaxf(ss * (1.0f / NG) - mean * mean, 0.f);
  float rstd = rsqrtf(var + EPS);
  float ga = gam[c] * rstd;
  float bb = bet[c] - mean * ga;
#pragma unroll 8
  for (int m = 0; m < NG; m++)
    z[(size_t)m * ZLD + TRI + c] = f2bf(hp[m * 384 + c] * ga + bb);
}

// triu gather + BN of raw connectome -> z[:, 0:TRI). One block per row i.
__global__ __launch_bounds__(256) void k_x0bn(
    const float* __restrict__ x, const float* __restrict__ gam,
    const float* __restrict__ bet, u16* __restrict__ z) {
  int i = blockIdx.x;                             // 0..359
  int off = i * FN - (i * (i - 1)) / 2;
  for (int j = i + (int)threadIdx.x; j < FN; j += 256) {
    float s = 0.f, ss = 0.f;
#pragma unroll 8
    for (int b = 0; b < NG; b++) {
      float v = x[(size_t)(b * FN + i) * FN + j];
      s += v; ss += v * v;
    }
    float mean = s * (1.0f / NG);
    float var = fmaxf(ss * (1.0f / NG) - mean * mean, 0.f);
    float rstd = rsqrtf(var + EPS);
    int f = off + (j - i);
    float ga = gam[f] * rstd;
    float bb = bet[f] - mean * ga;
#pragma unroll 8
    for (int b = 0; b < NG; b++) {
      float v = x[(size_t)(b * FN + i) * FN + j];
      z[(size_t)b * ZLD + f] = f2bf(v * ga + bb);
    }
  }
}

// BN + ReLU + bf16 cast: grid (N/64); block 256 = 64 channels x 4 row-groups of 32.
__global__ __launch_bounds__(256) void k_bnrelu(
    const float* __restrict__ y, const float* __restrict__ gam,
    const float* __restrict__ bet, u16* __restrict__ a, int N) {
  __shared__ float sb[4][64], sb2[4][64];
  int c63 = threadIdx.x & 63;
  int grp = threadIdx.x >> 6;                     // 0..3
  int c = blockIdx.x * 64 + c63;
  float s = 0.f, ss = 0.f;
#pragma unroll 8
  for (int m = grp * 32; m < grp * 32 + 32; m++) {
    float v = y[(size_t)m * N + c]; s += v; ss += v * v;
  }
  sb[grp][c63] = s; sb2[grp][c63] = ss;
  __syncthreads();
  float S = sb[0][c63] + sb[1][c63] + sb[2][c63] + sb[3][c63];
  float SS = sb2[0][c63] + sb2[1][c63] + sb2[2][c63] + sb2[3][c63];
  float mean = S * (1.0f / NG);
  float var = fmaxf(SS * (1.0f / NG) - mean * mean, 0.f);
  float rstd = rsqrtf(var + EPS);
  float ga = gam[c] * rstd;
  float bb = bet[c] - mean * ga;
#pragma unroll 8
  for (int m = grp * 32; m < grp * 32 + 32; m++) {
    float v = y[(size_t)m * N + c] * ga + bb;
    a[(size_t)m * N + c] = f2bf(fmaxf(v, 0.f));
  }
}

__global__ void k_head(const u16* __restrict__ a3, const float* __restrict__ W4,
                       const float* __restrict__ b4, float* __restrict__ out) {
  __shared__ float w4s[H2 * 2];
  int m = threadIdx.x;                            // block 128
  for (int i = m; i < H2 * 2; i += 128) w4s[i] = W4[i];
  __syncthreads();
  float a0 = b4[0], a1 = b4[1];
  for (int k0 = 0; k0 < H2; k0 += 8) {
    bf16x8 v = *(const bf16x8*)(a3 + (size_t)m * H2 + k0);
#pragma unroll
    for (int j = 0; j < 8; j++) {
      float f = bf2f((u16)v[j]);
      a0 += f * w4s[(k0 + j) * 2];
      a1 += f * w4s[(k0 + j) * 2 + 1];
    }
  }
  float mx = fmaxf(a0, a1);
  float lse = mx + logf(expf(a0 - mx) + expf(a1 - mx));
  out[m * 2]     = a0 - lse;
  out[m * 2 + 1] = a1 - lse;
}

// ---------------- launch ----------------
extern "C" void kernel_launch(void* const* d_in, const int* in_sizes, int n_in,
                              void* d_out, int out_size, void* d_ws, size_t ws_size,
                              hipStream_t stream) {
  const float* x    = (const float*)d_in[0];
  const int* esrc   = (const int*)d_in[1];
  const int* edst   = (const int*)d_in[2];
  // d_in[3] = batch (uniform 360 nodes/graph; unused)
  const float* Wc1 = (const float*)d_in[4];  const float* bc1 = (const float*)d_in[5];
  const float* Wc2 = (const float*)d_in[6];  const float* bc2 = (const float*)d_in[7];
  const float* Wc3 = (const float*)d_in[8];  const float* bc3 = (const float*)d_in[9];
  const float* bn_g = (const float*)d_in[10]; const float* bn_b = (const float*)d_in[11];
  const float* bnh_g = (const float*)d_in[12]; const float* bnh_b = (const float*)d_in[13];
  const float* W1 = (const float*)d_in[14]; const float* b1 = (const float*)d_in[15];
  const float* g1 = (const float*)d_in[16]; const float* be1 = (const float*)d_in[17];
  const float* W2 = (const float*)d_in[18]; const float* b2 = (const float*)d_in[19];
  const float* g2 = (const float*)d_in[20]; const float* be2 = (const float*)d_in[21];
  const float* W3 = (const float*)d_in[22]; const float* b3 = (const float*)d_in[23];
  const float* g3 = (const float*)d_in[24]; const float* be3 = (const float*)d_in[25];
  const float* W4 = (const float*)d_in[26]; const float* b4 = (const float*)d_in[27];

  char* ws = (char*)d_ws;
  float* A32  = (float*)(ws + A32_OFF);
  u16*   Ab   = (u16*)(ws + AB_OFF);
  float* dinv = (float*)(ws + DEG_OFF);
  u16*   PT   = (u16*)(ws + P_OFF);
  u16*   hA   = (u16*)(ws + HA_OFF);
  u16*   hB   = (u16*)(ws + HB_OFF);
  float* hp   = (float*)(ws + HP_OFF);
  u16*   z    = (u16*)(ws + Z_OFF);
  float* y1   = (float*)(ws + Y1_OFF);
  u16*   a1   = (u16*)(ws + A1_OFF);
  float* y2   = (float*)(ws + Y2_OFF);
  u16*   a2   = (u16*)(ws + A2_OFF);
  float* y3   = (float*)(ws + Y3_OFF);
  u16*   a3   = (u16*)(ws + A3_OFF);
  float* part = (float*)(ws + PART_OFF);

  // zero accumulators (ws is poisoned 0xAA before every call)
  (void)hipMemsetAsync(dinv, 0, (size_t)NN * 4, stream);
  (void)hipMemsetAsync(A32, 0, (size_t)NG * FN * FN * 4, stream);

  dim3 b256(256);
  // graph structure
  k_deg<<<dim3((NE + 255) / 256), b256, 0, stream>>>(edst, dinv);
  k_dinv<<<dim3((NN + 255) / 256), b256, 0, stream>>>(dinv);
  k_abuild<<<dim3((NE + 255) / 256), b256, 0, stream>>>(esrc, edst, dinv, A32);
  k_aconv<<<dim3(NG * FN * FN / 256), b256, 0, stream>>>(A32, Ab, dinv);

  // z lives in region0 which aliases A32 — issue its clear after k_aconv.
  (void)hipMemsetAsync(z, 0, (size_t)NG * ZLD * 2, stream);

  // GCN layer 1 (x is f32)
  k_gemm_xw_f32<<<dim3(NN / 64), b256, 0, stream>>>(x, Wc1, PT, FN);
  k_gemm_agg<<<dim3(2, 6, NG), b256, 0, stream>>>(Ab, PT, bc1, hA);
  k_pool<<<dim3(NG), dim3(128), 0, stream>>>(hA, hp, 0);
  // GCN layer 2
  k_gemm_xw_bf16<<<dim3(NN / 64), b256, 0, stream>>>(hA, Wc2, PT);
  k_gemm_agg<<<dim3(2, 6, NG), b256, 0, stream>>>(Ab, PT, bc2, hB);
  k_pool<<<dim3(NG), dim3(128), 0, stream>>>(hB, hp, 1);
  // GCN layer 3
  k_gemm_xw_bf16<<<dim3(NN / 64), b256, 0, stream>>>(hB, Wc3, PT);
  k_gemm_agg<<<dim3(2, 6, NG), b256, 0, stream>>>(Ab, PT, bc3, hA);
  k_pool<<<dim3(NG), dim3(128), 0, stream>>>(hA, hp, 2);

  // feature assembly: z = [BN(triu(x)) | BN(pooled h)]
  k_x0bn<<<dim3(FN), b256, 0, stream>>>(x, bn_g, bn_b, z);
  k_hbn<<<dim3(1), dim3(384), 0, stream>>>(hp, bnh_g, bnh_b, z);

  // MLP head
  k_gemm_big<<<dim3(4, NSPLIT), b256, 0, stream>>>(z, W1, part);
  k_red<<<dim3(65536 / 256), b256, 0, stream>>>(part, b1, y1);
  k_bnrelu<<<dim3(H1 / 64), b256, 0, stream>>>(y1, g1, be1, a1, H1);
  k_mlp_gemm<<<dim3(H2 / 64), b256, 0, stream>>>(a1, W2, b2, y2, H1, H2);
  k_bnrelu<<<dim3(H2 / 64), b256, 0, stream>>>(y2, g2, be2, a2, H2);
  k_mlp_gemm<<<dim3(H2 / 64), b256, 0, stream>>>(a2, W3, b3, y3, H2, H2);
  k_bnrelu<<<dim3(H2 / 64), b256, 0, stream>>>(y3, g3, be3, a3, H2);
  k_head<<<dim3(1), dim3(128), 0, stream>>>(a3, W4, b4, (float*)d_out);
}

// Round 6
// 665.676 us; speedup vs baseline: 2.1975x; 1.1699x over previous
//
#include <hip/hip_runtime.h>
#include <hip/hip_bf16.h>
#include <math.h>

// ---------------- problem constants ----------------
#define FN 360            // nodes per graph == features
#define NG 128            // graphs
#define NN 46080          // NG*FN
#define CH 128            // hidden channels
#define NE 1000000        // edges
#define TRI 64980         // FN*(FN+1)/2
#define D1 65364          // TRI + 3*CH
#define ZLD 65376         // D1 padded to multiple of 32 (zeroed tail)
#define H1 512
#define H2 256
#define EPS 1e-5f
#define NSPLIT 128        // split-K for the big GEMM (chunk = 512)

typedef unsigned short u16;
typedef __attribute__((ext_vector_type(8))) short bf16x8;
typedef __attribute__((ext_vector_type(4))) float f32x4;

__device__ __forceinline__ float bf2f(u16 v) {
  union { unsigned u; float f; } x; x.u = ((unsigned)v) << 16; return x.f;
}
__device__ __forceinline__ u16 f2bf(float f) {
  union { float f; unsigned u; } x; x.f = f;
  unsigned r = x.u + 0x7fffu + ((x.u >> 16) & 1u);   // RNE
  return (u16)(r >> 16);
}
__device__ __forceinline__ bf16x8 bzero8() {
  bf16x8 z;
#pragma unroll
  for (int j = 0; j < 8; j++) z[j] = 0;
  return z;
}

// ---------------- workspace layout (bytes), max ~130.9 MB ----------------
static const size_t A32_OFF  = 0;                        // f32 [NG*FN*FN] 66,355,200
static const size_t DINV_OFF = 66355200;                 // f32 [NN] 184,320 (memset w/ A32)
static const size_t Z_OFF    = 66539520;                 // bf16 [NG*ZLD] 16,736,256
static const size_t PT_OFF   = 83275776;                 // bf16 [NN*CH] 11,796,480
static const size_t H1_OFF   = 95072256;                 // bf16 [NN*CH]
static const size_t H2_OFF   = 106868736;                // bf16 [NN*CH]
static const size_t H3_OFF   = 118665216;                // bf16 [NN*CH]
static const size_t HP_OFF   = 130461696;                // f32 [NG*384]
static const size_t A1_OFF   = 130658304;                // bf16 [NG*H1]
static const size_t A2_OFF   = 130789376;                // bf16 [NG*H2]
static const size_t A3_OFF   = 130854912;                // bf16 [NG*H2]
static const size_t Y1_OFF   = 130920448;                // f32 [NG*H1] 262,144
static const size_t PART_OFF = 0;                        // f32 [NSPLIT*NG*H1] 33.5MB, aliases A32 (dead after agg3)

// ---------------- graph-structure kernels ----------------
__global__ void k_deg(const int* __restrict__ dst, float* __restrict__ deg) {
  int e = blockIdx.x * 256 + threadIdx.x;
  if (e < NE) atomicAdd(&deg[dst[e]], 1.0f);
}

__global__ void k_dinv(float* __restrict__ deg) {
  int i = blockIdx.x * 256 + threadIdx.x;
  if (i < NN) deg[i] = rsqrtf(deg[i] + 1.0f);   // +1: self loop
}

// edges + self-loop diagonal in one pass
__global__ void k_abuild(const int* __restrict__ src, const int* __restrict__ dst,
                         const float* __restrict__ dinv, float* __restrict__ A) {
  int e = blockIdx.x * 256 + threadIdx.x;
  if (e < NE) {
    int s = src[e], d = dst[e];
    int g = d / FN;
    int ls = s - g * FN, ld = d - g * FN;
    atomicAdd(&A[(size_t)g * FN * FN + (size_t)ld * FN + ls], dinv[s] * dinv[d]);
  } else if (e < NE + NN) {
    int i = e - NE;
    int g = i / FN, l = i - g * FN;
    float dv = dinv[i];
    atomicAdd(&A[(size_t)g * FN * FN + (size_t)l * FN + l], dv * dv);
  }
}

// ------- MFMA GEMM (f32 A): PT = (X[M][K] @ W[K][128])^T per graph -------
__global__ __launch_bounds__(256) void k_gemm_xw_f32(
    const float* __restrict__ X, const float* __restrict__ W,
    u16* __restrict__ PT, int K) {
  __shared__ __attribute__((aligned(16))) u16 WT[128][40];
  int wid = threadIdx.x >> 6, lane = threadIdx.x & 63;
  int quad = lane >> 4, l16 = lane & 15;
  int m0 = blockIdx.x * 64 + (wid & 1) * 32;
  int n0w = (wid >> 1) * 64;
  int kl = threadIdx.x >> 3, nseg = (threadIdx.x & 7) * 16;
  f32x4 acc[2][4];
#pragma unroll
  for (int i = 0; i < 2; i++)
#pragma unroll
    for (int j = 0; j < 4; j++) acc[i][j] = (f32x4){0,0,0,0};
  for (int k0 = 0; k0 < K; k0 += 32) {
    __syncthreads();
    int kg = k0 + kl;
    if (kg < K) {
      const float* wrow = W + (size_t)kg * CH + nseg;
      f32x4 w0 = *(const f32x4*)(wrow);
      f32x4 w1 = *(const f32x4*)(wrow + 4);
      f32x4 w2 = *(const f32x4*)(wrow + 8);
      f32x4 w3 = *(const f32x4*)(wrow + 12);
#pragma unroll
      for (int j = 0; j < 4; j++) {
        WT[nseg + j][kl]      = f2bf(w0[j]);
        WT[nseg + 4 + j][kl]  = f2bf(w1[j]);
        WT[nseg + 8 + j][kl]  = f2bf(w2[j]);
        WT[nseg + 12 + j][kl] = f2bf(w3[j]);
      }
    } else {
#pragma unroll
      for (int j = 0; j < 16; j++) WT[nseg + j][kl] = 0;
    }
    __syncthreads();
    int kk = k0 + quad * 8;
    bool kin = kk < K;
    bf16x8 af[2];
#pragma unroll
    for (int tm = 0; tm < 2; tm++) {
      int row = m0 + tm * 16 + l16;
      bf16x8 a = bzero8();
      if (kin) {
        f32x4 va = *(const f32x4*)(X + (size_t)row * K + kk);
        f32x4 vb = *(const f32x4*)(X + (size_t)row * K + kk + 4);
#pragma unroll
        for (int j = 0; j < 4; j++) { a[j] = (short)f2bf(va[j]); a[4 + j] = (short)f2bf(vb[j]); }
      }
      af[tm] = a;
    }
    bf16x8 bfr[4];
#pragma unroll
    for (int tn = 0; tn < 4; tn++)
      bfr[tn] = *(const bf16x8*)&WT[n0w + tn * 16 + l16][quad * 8];
#pragma unroll
    for (int tm = 0; tm < 2; tm++)
#pragma unroll
      for (int tn = 0; tn < 4; tn++)
        acc[tm][tn] = __builtin_amdgcn_mfma_f32_16x16x32_bf16(af[tm], bfr[tn], acc[tm][tn], 0, 0, 0);
  }
#pragma unroll
  for (int tm = 0; tm < 2; tm++)
#pragma unroll
    for (int tn = 0; tn < 4; tn++) {
      int col = n0w + tn * 16 + l16;
      int rowb = m0 + tm * 16 + quad * 4;
#pragma unroll
      for (int r = 0; r < 4; r++) {
        int row = rowb + r;
        int g = row / FN, lr = row - g * FN;
        PT[((size_t)g * CH + col) * FN + lr] = f2bf(acc[tm][tn][r]);
      }
    }
}

// ------- MFMA GEMM (bf16 A [M][128]): PT = (X @ W)^T per graph, W f32 -------
__global__ __launch_bounds__(256) void k_gemm_xw_bf16(
    const u16* __restrict__ X, const float* __restrict__ W,
    u16* __restrict__ PT) {
  __shared__ __attribute__((aligned(16))) u16 WT[128][40];
  int wid = threadIdx.x >> 6, lane = threadIdx.x & 63;
  int quad = lane >> 4, l16 = lane & 15;
  int m0 = blockIdx.x * 64 + (wid & 1) * 32;
  int n0w = (wid >> 1) * 64;
  int kl = threadIdx.x >> 3, nseg = (threadIdx.x & 7) * 16;
  f32x4 acc[2][4];
#pragma unroll
  for (int i = 0; i < 2; i++)
#pragma unroll
    for (int j = 0; j < 4; j++) acc[i][j] = (f32x4){0,0,0,0};
  for (int k0 = 0; k0 < CH; k0 += 32) {
    __syncthreads();
    int kg = k0 + kl;
    const float* wrow = W + (size_t)kg * CH + nseg;
    f32x4 w0 = *(const f32x4*)(wrow);
    f32x4 w1 = *(const f32x4*)(wrow + 4);
    f32x4 w2 = *(const f32x4*)(wrow + 8);
    f32x4 w3 = *(const f32x4*)(wrow + 12);
#pragma unroll
    for (int j = 0; j < 4; j++) {
      WT[nseg + j][kl]      = f2bf(w0[j]);
      WT[nseg + 4 + j][kl]  = f2bf(w1[j]);
      WT[nseg + 8 + j][kl]  = f2bf(w2[j]);
      WT[nseg + 12 + j][kl] = f2bf(w3[j]);
    }
    __syncthreads();
    int kk = k0 + quad * 8;
    bf16x8 af[2];
#pragma unroll
    for (int tm = 0; tm < 2; tm++) {
      int row = m0 + tm * 16 + l16;
      af[tm] = *(const bf16x8*)(X + (size_t)row * CH + kk);
    }
    bf16x8 bfr[4];
#pragma unroll
    for (int tn = 0; tn < 4; tn++)
      bfr[tn] = *(const bf16x8*)&WT[n0w + tn * 16 + l16][quad * 8];
#pragma unroll
    for (int tm = 0; tm < 2; tm++)
#pragma unroll
      for (int tn = 0; tn < 4; tn++)
        acc[tm][tn] = __builtin_amdgcn_mfma_f32_16x16x32_bf16(af[tm], bfr[tn], acc[tm][tn], 0, 0, 0);
  }
#pragma unroll
  for (int tm = 0; tm < 2; tm++)
#pragma unroll
    for (int tn = 0; tn < 4; tn++) {
      int col = n0w + tn * 16 + l16;
      int rowb = m0 + tm * 16 + quad * 4;
#pragma unroll
      for (int r = 0; r < 4; r++) {
        int row = rowb + r;
        int g = row / FN, lr = row - g * FN;
        PT[((size_t)g * CH + col) * FN + lr] = f2bf(acc[tm][tn][r]);
      }
    }
}

// ------- aggregation: H_g = tanh(A_g(f32) @ P_g + bias) -------
// linear grid NG*6, XCD-swizzled: g=(id&7)+8*(id/48), mb=(id%48)>>3.
// BM=64, BN=128; 4 waves: (wid&1)->m-half, (wid>>1)->n-half.
__global__ __launch_bounds__(256) void k_gemm_agg(
    const float* __restrict__ A32, const u16* __restrict__ PT,
    const float* __restrict__ bias, u16* __restrict__ Hout) {
  int id = blockIdx.x;
  int g = (id & 7) + 8 * (id / 48);
  int mb = (id % 48) >> 3;
  int wid = threadIdx.x >> 6, lane = threadIdx.x & 63;
  int quad = lane >> 4, l16 = lane & 15;
  int m0 = mb * 64 + (wid & 1) * 32;
  int n0 = (wid >> 1) * 64;
  const float* Ag = A32 + (size_t)g * FN * FN;
  const u16* PTg = PT + (size_t)g * CH * FN;
  f32x4 acc[2][4];
#pragma unroll
  for (int i = 0; i < 2; i++)
#pragma unroll
    for (int j = 0; j < 4; j++) acc[i][j] = (f32x4){0,0,0,0};
  for (int k0 = 0; k0 < FN; k0 += 32) {
    int kk = k0 + quad * 8;
    bool kin = kk < FN;
    bf16x8 af[2];
#pragma unroll
    for (int tm = 0; tm < 2; tm++) {
      int row = m0 + tm * 16 + l16;
      bf16x8 a = bzero8();
      if (kin && row < FN) {
        f32x4 va = *(const f32x4*)(Ag + (size_t)row * FN + kk);
        f32x4 vb = *(const f32x4*)(Ag + (size_t)row * FN + kk + 4);
#pragma unroll
        for (int j = 0; j < 4; j++) { a[j] = (short)f2bf(va[j]); a[4 + j] = (short)f2bf(vb[j]); }
      }
      af[tm] = a;
    }
    bf16x8 bfr[4];
#pragma unroll
    for (int tn = 0; tn < 4; tn++) {
      int col = n0 + tn * 16 + l16;
      bfr[tn] = kin ? *(const bf16x8*)(PTg + (size_t)col * FN + kk) : bzero8();
    }
#pragma unroll
    for (int tm = 0; tm < 2; tm++)
#pragma unroll
      for (int tn = 0; tn < 4; tn++)
        acc[tm][tn] = __builtin_amdgcn_mfma_f32_16x16x32_bf16(af[tm], bfr[tn], acc[tm][tn], 0, 0, 0);
  }
#pragma unroll
  for (int tm = 0; tm < 2; tm++)
#pragma unroll
    for (int tn = 0; tn < 4; tn++) {
      int col = n0 + tn * 16 + l16;
      float bc = bias[col];
      int rowb = m0 + tm * 16 + quad * 4;
#pragma unroll
      for (int r = 0; r < 4; r++) {
        int row = rowb + r;
        if (row < FN)
          Hout[(size_t)(g * FN + row) * CH + col] = f2bf(tanhf(acc[tm][tn][r] + bc));
      }
    }
}

// ------- big GEMM: part[s] = Z[128][chunk] @ W1[chunk][512], XCD-swizzled -------
__global__ __launch_bounds__(256) void k_gemm_big(
    const u16* __restrict__ Z, const float* __restrict__ W1f, float* __restrict__ part) {
  __shared__ __attribute__((aligned(16))) u16 WT[128][40];
  int id = blockIdx.x;                         // 0..511
  int s = (id & 7) + 8 * (id >> 5);
  int n0b = ((id >> 3) & 3) * 128;
  int wid = threadIdx.x >> 6, lane = threadIdx.x & 63;
  int quad = lane >> 4, l16 = lane & 15;
  int m0 = wid * 32;
  int kl = threadIdx.x >> 3, nseg = (threadIdx.x & 7) * 16;
  int kbeg = s * 512;
  int kend = (ZLD < kbeg + 512) ? ZLD : (kbeg + 512);
  f32x4 acc[2][8];
#pragma unroll
  for (int i = 0; i < 2; i++)
#pragma unroll
    for (int j = 0; j < 8; j++) acc[i][j] = (f32x4){0,0,0,0};
  for (int k0 = kbeg; k0 < kend; k0 += 32) {
    __syncthreads();
    int kg = k0 + kl;
    if (kg < D1) {
      const float* wrow = W1f + (size_t)kg * H1 + n0b + nseg;
      f32x4 w0 = *(const f32x4*)(wrow);
      f32x4 w1 = *(const f32x4*)(wrow + 4);
      f32x4 w2 = *(const f32x4*)(wrow + 8);
      f32x4 w3 = *(const f32x4*)(wrow + 12);
#pragma unroll
      for (int j = 0; j < 4; j++) {
        WT[nseg + j][kl]      = f2bf(w0[j]);
        WT[nseg + 4 + j][kl]  = f2bf(w1[j]);
        WT[nseg + 8 + j][kl]  = f2bf(w2[j]);
        WT[nseg + 12 + j][kl] = f2bf(w3[j]);
      }
    } else {
#pragma unroll
      for (int j = 0; j < 16; j++) WT[nseg + j][kl] = 0;
    }
    __syncthreads();
    int kk = k0 + quad * 8;
    bf16x8 af[2];
#pragma unroll
    for (int tm = 0; tm < 2; tm++) {
      int row = m0 + tm * 16 + l16;
      af[tm] = *(const bf16x8*)(Z + (size_t)row * ZLD + kk);
    }
    bf16x8 bfr[8];
#pragma unroll
    for (int tn = 0; tn < 8; tn++)
      bfr[tn] = *(const bf16x8*)&WT[tn * 16 + l16][quad * 8];
#pragma unroll
    for (int tm = 0; tm < 2; tm++)
#pragma unroll
      for (int tn = 0; tn < 8; tn++)
        acc[tm][tn] = __builtin_amdgcn_mfma_f32_16x16x32_bf16(af[tm], bfr[tn], acc[tm][tn], 0, 0, 0);
  }
#pragma unroll
  for (int tm = 0; tm < 2; tm++)
#pragma unroll
    for (int tn = 0; tn < 8; tn++) {
      int col = n0b + tn * 16 + l16;
      int rowb = m0 + tm * 16 + quad * 4;
#pragma unroll
      for (int r = 0; r < 4; r++)
        part[((size_t)s * NG + rowb + r) * H1 + col] = acc[tm][tn][r];
    }
}

__global__ void k_red(const float* __restrict__ part, float* __restrict__ y1) {
  int idx = blockIdx.x * 256 + threadIdx.x;       // < 65536
  float s = 0.f;
#pragma unroll 8
  for (int i = 0; i < NSPLIT; i++) s += part[(size_t)i * 65536 + idx];
  y1[idx] = s;                                    // bias dropped: BN cancels it
}

// BN + ReLU + bf16 cast: grid (N/64); block 256 = 64 channels x 4 row-groups of 32.
__global__ __launch_bounds__(256) void k_bnrelu(
    const float* __restrict__ y, const float* __restrict__ gam,
    const float* __restrict__ bet, u16* __restrict__ a, int N) {
  __shared__ float sb[4][64], sb2[4][64];
  int c63 = threadIdx.x & 63;
  int grp = threadIdx.x >> 6;
  int c = blockIdx.x * 64 + c63;
  float s = 0.f, ss = 0.f;
#pragma unroll 8
  for (int m = grp * 32; m < grp * 32 + 32; m++) {
    float v = y[(size_t)m * N + c]; s += v; ss += v * v;
  }
  sb[grp][c63] = s; sb2[grp][c63] = ss;
  __syncthreads();
  float S = sb[0][c63] + sb[1][c63] + sb[2][c63] + sb[3][c63];
  float SS = sb2[0][c63] + sb2[1][c63] + sb2[2][c63] + sb2[3][c63];
  float mean = S * (1.0f / NG);
  float var = fmaxf(SS * (1.0f / NG) - mean * mean, 0.f);
  float rstd = rsqrtf(var + EPS);
  float ga = gam[c] * rstd;
  float bb = bet[c] - mean * ga;
#pragma unroll 8
  for (int m = grp * 32; m < grp * 32 + 32; m++) {
    float v = y[(size_t)m * N + c] * ga + bb;
    a[(size_t)m * N + c] = f2bf(fmaxf(v, 0.f));
  }
}

// ------- fused MLP GEMM + BN + ReLU: a_out = relu(bn(A@W)) -------
// grid (N/64); block 256 = 4 waves; each wave 32 m-rows; block covers all 128 m.
__global__ __launch_bounds__(256) void k_mlpbn(
    const u16* __restrict__ A, const float* __restrict__ W,
    const float* __restrict__ gam, const float* __restrict__ bet,
    u16* __restrict__ aout, int K, int N) {
  __shared__ __attribute__((aligned(16))) u16 WT[64][40];
  __shared__ float rs[4][4][4][16], rss[4][4][4][16];   // [wid][quad][tn][l16]
  int wid = threadIdx.x >> 6, lane = threadIdx.x & 63;
  int quad = lane >> 4, l16 = lane & 15;
  int n0b = blockIdx.x * 64;
  int m0 = wid * 32;
  int kl = threadIdx.x >> 3;          // 0..31
  int nseg = (threadIdx.x & 7) * 8;   // 0..56
  f32x4 acc[2][4];
#pragma unroll
  for (int i = 0; i < 2; i++)
#pragma unroll
    for (int j = 0; j < 4; j++) acc[i][j] = (f32x4){0,0,0,0};
  for (int k0 = 0; k0 < K; k0 += 32) {
    __syncthreads();
    const float* wrow = W + (size_t)(k0 + kl) * N + n0b + nseg;
    f32x4 w0 = *(const f32x4*)(wrow);
    f32x4 w1 = *(const f32x4*)(wrow + 4);
#pragma unroll
    for (int j = 0; j < 4; j++) {
      WT[nseg + j][kl]     = f2bf(w0[j]);
      WT[nseg + 4 + j][kl] = f2bf(w1[j]);
    }
    __syncthreads();
    int kk = k0 + quad * 8;
    bf16x8 af[2];
#pragma unroll
    for (int tm = 0; tm < 2; tm++) {
      int row = m0 + tm * 16 + l16;
      af[tm] = *(const bf16x8*)(A + (size_t)row * K + kk);
    }
    bf16x8 bfr[4];
#pragma unroll
    for (int tn = 0; tn < 4; tn++)
      bfr[tn] = *(const bf16x8*)&WT[tn * 16 + l16][quad * 8];
#pragma unroll
    for (int tm = 0; tm < 2; tm++)
#pragma unroll
      for (int tn = 0; tn < 4; tn++)
        acc[tm][tn] = __builtin_amdgcn_mfma_f32_16x16x32_bf16(af[tm], bfr[tn], acc[tm][tn], 0, 0, 0);
  }
  // per-lane partial stats (8 rows per tn), reduce over wid x quad via LDS
  __syncthreads();
#pragma unroll
  for (int tn = 0; tn < 4; tn++) {
    float s = 0.f, ss = 0.f;
#pragma unroll
    for (int tm = 0; tm < 2; tm++)
#pragma unroll
      for (int r = 0; r < 4; r++) { float v = acc[tm][tn][r]; s += v; ss += v * v; }
    rs[wid][quad][tn][l16] = s;
    rss[wid][quad][tn][l16] = ss;
  }
  __syncthreads();
#pragma unroll
  for (int tn = 0; tn < 4; tn++) {
    float S = 0.f, SS = 0.f;
#pragma unroll
    for (int w = 0; w < 4; w++)
#pragma unroll
      for (int q = 0; q < 4; q++) { S += rs[w][q][tn][l16]; SS += rss[w][q][tn][l16]; }
    float mean = S * (1.0f / NG);
    float var = fmaxf(SS * (1.0f / NG) - mean * mean, 0.f);
    float rstd = rsqrtf(var + EPS);
    int col = n0b + tn * 16 + l16;
    float ga = gam[col] * rstd;
    float bb = bet[col] - mean * ga;
#pragma unroll
    for (int tm = 0; tm < 2; tm++) {
      int rowb = m0 + tm * 16 + quad * 4;
#pragma unroll
      for (int r = 0; r < 4; r++) {
        float v = acc[tm][tn][r] * ga + bb;
        aout[(size_t)(rowb + r) * N + col] = f2bf(fmaxf(v, 0.f));
      }
    }
  }
}

// ---------------- pooling / batch-norm kernels ----------------
// one kernel for all 3 layers: grid (NG, 3), block 128
__global__ void k_pool3(const u16* __restrict__ h1, const u16* __restrict__ h2,
                        const u16* __restrict__ h3, float* __restrict__ hp) {
  int g = blockIdx.x, layer = blockIdx.y, c = threadIdx.x;
  const u16* h = (layer == 0) ? h1 : (layer == 1) ? h2 : h3;
  float s = 0.f;
#pragma unroll 8
  for (int r = 0; r < FN; r++) s += bf2f(h[(size_t)(g * FN + r) * CH + c]);
  hp[g * 384 + layer * CH + c] = s * (1.0f / FN);
}

// blocks 0..359: triu gather + BN of raw connectome -> z[:, 0:TRI)
// block 360: hbn (pooled-h BN -> z[:, TRI:TRI+384)) + zero z pad cols [D1,ZLD)
__global__ __launch_bounds__(256) void k_x0bn(
    const float* __restrict__ x, const float* __restrict__ gam,
    const float* __restrict__ bet, const float* __restrict__ hp,
    const float* __restrict__ hgam, const float* __restrict__ hbet,
    u16* __restrict__ z) {
  int i = blockIdx.x;
  if (i < FN) {
    int off = i * FN - (i * (i - 1)) / 2;
    for (int j = i + (int)threadIdx.x; j < FN; j += 256) {
      float s = 0.f, ss = 0.f;
#pragma unroll 8
      for (int b = 0; b < NG; b++) {
        float v = x[(size_t)(b * FN + i) * FN + j];
        s += v; ss += v * v;
      }
      float mean = s * (1.0f / NG);
      float var = fmaxf(ss * (1.0f / NG) - mean * mean, 0.f);
      float rstd = rsqrtf(var + EPS);
      int f = off + (j - i);
      float ga = gam[f] * rstd;
      float bb = bet[f] - mean * ga;
#pragma unroll 8
      for (int b = 0; b < NG; b++) {
        float v = x[(size_t)(b * FN + i) * FN + j];
        z[(size_t)b * ZLD + f] = f2bf(v * ga + bb);
      }
    }
  } else {
    for (int c = threadIdx.x; c < 384; c += 256) {
      float s = 0.f, ss = 0.f;
#pragma unroll 8
      for (int m = 0; m < NG; m++) { float v = hp[m * 384 + c]; s += v; ss += v * v; }
      float mean = s * (1.0f / NG);
      float var = fmaxf(ss * (1.0f / NG) - mean * mean, 0.f);
      float rstd = rsqrtf(var + EPS);
      float ga = hgam[c] * rstd;
      float bb = hbet[c] - mean * ga;
#pragma unroll 8
      for (int m = 0; m < NG; m++)
        z[(size_t)m * ZLD + TRI + c] = f2bf(hp[m * 384 + c] * ga + bb);
    }
    // zero the pad columns [D1, ZLD)
    if (threadIdx.x < NG) {
      for (int t = 0; t < ZLD - D1; t++)
        z[(size_t)threadIdx.x * ZLD + D1 + t] = 0;
    }
  }
}

__global__ void k_head(const u16* __restrict__ a3, const float* __restrict__ W4,
                       const float* __restrict__ b4, float* __restrict__ out) {
  __shared__ float w4s[H2 * 2];
  int m = threadIdx.x;                            // block 128
  for (int i = m; i < H2 * 2; i += 128) w4s[i] = W4[i];
  __syncthreads();
  float a0 = b4[0], a1 = b4[1];
  for (int k0 = 0; k0 < H2; k0 += 8) {
    bf16x8 v = *(const bf16x8*)(a3 + (size_t)m * H2 + k0);
#pragma unroll
    for (int j = 0; j < 8; j++) {
      float f = bf2f((u16)v[j]);
      a0 += f * w4s[(k0 + j) * 2];
      a1 += f * w4s[(k0 + j) * 2 + 1];
    }
  }
  float mx = fmaxf(a0, a1);
  float lse = mx + logf(expf(a0 - mx) + expf(a1 - mx));
  out[m * 2]     = a0 - lse;
  out[m * 2 + 1] = a1 - lse;
}

// ---------------- launch ----------------
extern "C" void kernel_launch(void* const* d_in, const int* in_sizes, int n_in,
                              void* d_out, int out_size, void* d_ws, size_t ws_size,
                              hipStream_t stream) {
  const float* x    = (const float*)d_in[0];
  const int* esrc   = (const int*)d_in[1];
  const int* edst   = (const int*)d_in[2];
  // d_in[3] = batch (uniform; unused)
  const float* Wc1 = (const float*)d_in[4];  const float* bc1 = (const float*)d_in[5];
  const float* Wc2 = (const float*)d_in[6];  const float* bc2 = (const float*)d_in[7];
  const float* Wc3 = (const float*)d_in[8];  const float* bc3 = (const float*)d_in[9];
  const float* bn_g = (const float*)d_in[10]; const float* bn_b = (const float*)d_in[11];
  const float* bnh_g = (const float*)d_in[12]; const float* bnh_b = (const float*)d_in[13];
  const float* W1 = (const float*)d_in[14];
  const float* g1 = (const float*)d_in[16]; const float* be1 = (const float*)d_in[17];
  const float* W2 = (const float*)d_in[18];
  const float* g2 = (const float*)d_in[20]; const float* be2 = (const float*)d_in[21];
  const float* W3 = (const float*)d_in[22];
  const float* g3 = (const float*)d_in[24]; const float* be3 = (const float*)d_in[25];
  const float* W4 = (const float*)d_in[26]; const float* b4 = (const float*)d_in[27];

  char* ws = (char*)d_ws;
  float* A32  = (float*)(ws + A32_OFF);
  float* dinv = (float*)(ws + DINV_OFF);
  u16*   z    = (u16*)(ws + Z_OFF);
  u16*   PT   = (u16*)(ws + PT_OFF);
  u16*   h1   = (u16*)(ws + H1_OFF);
  u16*   h2   = (u16*)(ws + H2_OFF);
  u16*   h3   = (u16*)(ws + H3_OFF);
  float* hp   = (float*)(ws + HP_OFF);
  u16*   a1   = (u16*)(ws + A1_OFF);
  u16*   a2   = (u16*)(ws + A2_OFF);
  u16*   a3   = (u16*)(ws + A3_OFF);
  float* y1   = (float*)(ws + Y1_OFF);
  float* part = (float*)(ws + PART_OFF);

  // one memset covers A32 + dinv (contiguous)
  (void)hipMemsetAsync(A32, 0, (size_t)NG * FN * FN * 4 + (size_t)NN * 4, stream);

  dim3 b256(256);
  k_deg<<<dim3((NE + 255) / 256), b256, 0, stream>>>(edst, dinv);
  k_dinv<<<dim3((NN + 255) / 256), b256, 0, stream>>>(dinv);
  k_abuild<<<dim3((NE + NN + 255) / 256), b256, 0, stream>>>(esrc, edst, dinv, A32);

  // GCN layers (A stays f32; agg converts in-register)
  k_gemm_xw_f32<<<dim3(NN / 64), b256, 0, stream>>>(x, Wc1, PT, FN);
  k_gemm_agg<<<dim3(NG * 6), b256, 0, stream>>>(A32, PT, bc1, h1);
  k_gemm_xw_bf16<<<dim3(NN / 64), b256, 0, stream>>>(h1, Wc2, PT);
  k_gemm_agg<<<dim3(NG * 6), b256, 0, stream>>>(A32, PT, bc2, h2);
  k_gemm_xw_bf16<<<dim3(NN / 64), b256, 0, stream>>>(h2, Wc3, PT);
  k_gemm_agg<<<dim3(NG * 6), b256, 0, stream>>>(A32, PT, bc3, h3);

  k_pool3<<<dim3(NG, 3), dim3(128), 0, stream>>>(h1, h2, h3, hp);
  k_x0bn<<<dim3(FN + 1), b256, 0, stream>>>(x, bn_g, bn_b, hp, bnh_g, bnh_b, z);

  // MLP head (part aliases A32 region; stream order guarantees A32 is dead)
  k_gemm_big<<<dim3(512), b256, 0, stream>>>(z, W1, part);
  k_red<<<dim3(65536 / 256), b256, 0, stream>>>(part, y1);
  k_bnrelu<<<dim3(H1 / 64), b256, 0, stream>>>(y1, g1, be1, a1, H1);
  k_mlpbn<<<dim3(H2 / 64), b256, 0, stream>>>(a1, W2, g2, be2, a2, H1, H2);
  k_mlpbn<<<dim3(H2 / 64), b256, 0, stream>>>(a2, W3, g3, be3, a3, H2, H2);
  k_head<<<dim3(1), dim3(128), 0, stream>>>(a3, W4, b4, (float*)d_out);
}

// Round 7
// 648.118 us; speedup vs baseline: 2.2570x; 1.0271x over previous
//
#include <hip/hip_runtime.h>
#include <hip/hip_bf16.h>
#include <math.h>

// ---------------- problem constants ----------------
#define FN 360            // nodes per graph == features
#define NG 128            // graphs
#define NN 46080          // NG*FN
#define CH 128            // hidden channels
#define NE 1000000        // edges
#define TRI 64980         // FN*(FN+1)/2
#define D1 65364          // TRI + 3*CH
#define ZLD 65376         // D1 padded to multiple of 32 (zeroed tail)
#define H1 512
#define H2 256
#define EPS 1e-5f
#define NSPLIT 128        // split-K for the big GEMM (chunk = 512)

typedef unsigned short u16;
typedef __attribute__((ext_vector_type(8))) short bf16x8;
typedef __attribute__((ext_vector_type(4))) float f32x4;

__device__ __forceinline__ float bf2f(u16 v) {
  union { unsigned u; float f; } x; x.u = ((unsigned)v) << 16; return x.f;
}
__device__ __forceinline__ u16 f2bf(float f) {
  union { float f; unsigned u; } x; x.f = f;
  unsigned r = x.u + 0x7fffu + ((x.u >> 16) & 1u);   // RNE
  return (u16)(r >> 16);
}
__device__ __forceinline__ bf16x8 bzero8() {
  bf16x8 z;
#pragma unroll
  for (int j = 0; j < 8; j++) z[j] = 0;
  return z;
}

// ---------------- workspace layout (bytes), peak ~123.5 MB ----------------
// region0 = A32 (f32 adjacency, 66,355,200 B). Dead after k_agg1; then reused:
//   z (bf16 NG*ZLD = 16,736,256) | part (f32 128*128*512 = 33,554,432) | y1/a1/a2/a3
static const size_t A32_OFF  = 0;
static const size_t Z_OFF    = 0;                        // aliases A32 (A32 dead)
static const size_t PART_OFF = 16736256;
static const size_t Y1_OFF   = 50290688;
static const size_t A1_OFF   = 50552832;
static const size_t A2_OFF   = 50683904;
static const size_t A3_OFF   = 50749440;                 // ends 50,814,976 < 66,355,200
static const size_t DEG_OFF  = 66355200;                 // f32 [NN] 184,320
static const size_t HP_OFF   = 66539520;                 // f32 [NG*384] 196,608 (memset w/ A32+deg)
static const size_t AB_OFF   = 66736128;                 // bf16 [NG*FN*FN] 33,177,600
static const size_t PT_OFF   = 99913728;                 // bf16 [NN*CH] 11,796,480
static const size_t H_OFF    = 111710208;                // bf16 [NN*CH] (h1 and h2 alias)

// ---------------- graph-structure kernels ----------------
__global__ void k_deg(const int* __restrict__ dst, float* __restrict__ deg) {
  int e = blockIdx.x * 256 + threadIdx.x;
  if (e < NE) atomicAdd(&deg[dst[e]], 1.0f);
}

// edges + self-loop diagonal; dinv computed on the fly (rsqrt(deg+1))
__global__ void k_abuild(const int* __restrict__ src, const int* __restrict__ dst,
                         const float* __restrict__ deg, float* __restrict__ A) {
  int e = blockIdx.x * 256 + threadIdx.x;
  if (e < NE) {
    int s = src[e], d = dst[e];
    int g = d / FN;
    int ls = s - g * FN, ld = d - g * FN;
    float w = rsqrtf(deg[s] + 1.0f) * rsqrtf(deg[d] + 1.0f);
    atomicAdd(&A[(size_t)g * FN * FN + (size_t)ld * FN + ls], w);
  } else if (e < NE + NN) {
    int i = e - NE;
    int g = i / FN, l = i - g * FN;
    float dv = rsqrtf(deg[i] + 1.0f);
    atomicAdd(&A[(size_t)g * FN * FN + (size_t)l * FN + l], dv * dv);
  }
}

// ------- MFMA GEMM (f32 A): PT = (X[M][K] @ W[K][128])^T per graph -------
__global__ __launch_bounds__(256) void k_gemm_xw_f32(
    const float* __restrict__ X, const float* __restrict__ W,
    u16* __restrict__ PT, int K) {
  __shared__ __attribute__((aligned(16))) u16 WT[128][40];
  int wid = threadIdx.x >> 6, lane = threadIdx.x & 63;
  int quad = lane >> 4, l16 = lane & 15;
  int m0 = blockIdx.x * 64 + (wid & 1) * 32;
  int n0w = (wid >> 1) * 64;
  int kl = threadIdx.x >> 3, nseg = (threadIdx.x & 7) * 16;
  f32x4 acc[2][4];
#pragma unroll
  for (int i = 0; i < 2; i++)
#pragma unroll
    for (int j = 0; j < 4; j++) acc[i][j] = (f32x4){0,0,0,0};
  for (int k0 = 0; k0 < K; k0 += 32) {
    __syncthreads();
    int kg = k0 + kl;
    if (kg < K) {
      const float* wrow = W + (size_t)kg * CH + nseg;
      f32x4 w0 = *(const f32x4*)(wrow);
      f32x4 w1 = *(const f32x4*)(wrow + 4);
      f32x4 w2 = *(const f32x4*)(wrow + 8);
      f32x4 w3 = *(const f32x4*)(wrow + 12);
#pragma unroll
      for (int j = 0; j < 4; j++) {
        WT[nseg + j][kl]      = f2bf(w0[j]);
        WT[nseg + 4 + j][kl]  = f2bf(w1[j]);
        WT[nseg + 8 + j][kl]  = f2bf(w2[j]);
        WT[nseg + 12 + j][kl] = f2bf(w3[j]);
      }
    } else {
#pragma unroll
      for (int j = 0; j < 16; j++) WT[nseg + j][kl] = 0;
    }
    __syncthreads();
    int kk = k0 + quad * 8;
    bool kin = kk < K;
    bf16x8 af[2];
#pragma unroll
    for (int tm = 0; tm < 2; tm++) {
      int row = m0 + tm * 16 + l16;
      bf16x8 a = bzero8();
      if (kin) {
        f32x4 va = *(const f32x4*)(X + (size_t)row * K + kk);
        f32x4 vb = *(const f32x4*)(X + (size_t)row * K + kk + 4);
#pragma unroll
        for (int j = 0; j < 4; j++) { a[j] = (short)f2bf(va[j]); a[4 + j] = (short)f2bf(vb[j]); }
      }
      af[tm] = a;
    }
    bf16x8 bfr[4];
#pragma unroll
    for (int tn = 0; tn < 4; tn++)
      bfr[tn] = *(const bf16x8*)&WT[n0w + tn * 16 + l16][quad * 8];
#pragma unroll
    for (int tm = 0; tm < 2; tm++)
#pragma unroll
      for (int tn = 0; tn < 4; tn++)
        acc[tm][tn] = __builtin_amdgcn_mfma_f32_16x16x32_bf16(af[tm], bfr[tn], acc[tm][tn], 0, 0, 0);
  }
#pragma unroll
  for (int tm = 0; tm < 2; tm++)
#pragma unroll
    for (int tn = 0; tn < 4; tn++) {
      int col = n0w + tn * 16 + l16;
      int rowb = m0 + tm * 16 + quad * 4;
#pragma unroll
      for (int r = 0; r < 4; r++) {
        int row = rowb + r;
        int g = row / FN, lr = row - g * FN;
        PT[((size_t)g * CH + col) * FN + lr] = f2bf(acc[tm][tn][r]);
      }
    }
}

// ------- MFMA GEMM (bf16 A [M][128]): PT = (X @ W)^T per graph, W f32 -------
__global__ __launch_bounds__(256) void k_gemm_xw_bf16(
    const u16* __restrict__ X, const float* __restrict__ W,
    u16* __restrict__ PT) {
  __shared__ __attribute__((aligned(16))) u16 WT[128][40];
  int wid = threadIdx.x >> 6, lane = threadIdx.x & 63;
  int quad = lane >> 4, l16 = lane & 15;
  int m0 = blockIdx.x * 64 + (wid & 1) * 32;
  int n0w = (wid >> 1) * 64;
  int kl = threadIdx.x >> 3, nseg = (threadIdx.x & 7) * 16;
  f32x4 acc[2][4];
#pragma unroll
  for (int i = 0; i < 2; i++)
#pragma unroll
    for (int j = 0; j < 4; j++) acc[i][j] = (f32x4){0,0,0,0};
  for (int k0 = 0; k0 < CH; k0 += 32) {
    __syncthreads();
    int kg = k0 + kl;
    const float* wrow = W + (size_t)kg * CH + nseg;
    f32x4 w0 = *(const f32x4*)(wrow);
    f32x4 w1 = *(const f32x4*)(wrow + 4);
    f32x4 w2 = *(const f32x4*)(wrow + 8);
    f32x4 w3 = *(const f32x4*)(wrow + 12);
#pragma unroll
    for (int j = 0; j < 4; j++) {
      WT[nseg + j][kl]      = f2bf(w0[j]);
      WT[nseg + 4 + j][kl]  = f2bf(w1[j]);
      WT[nseg + 8 + j][kl]  = f2bf(w2[j]);
      WT[nseg + 12 + j][kl] = f2bf(w3[j]);
    }
    __syncthreads();
    int kk = k0 + quad * 8;
    bf16x8 af[2];
#pragma unroll
    for (int tm = 0; tm < 2; tm++) {
      int row = m0 + tm * 16 + l16;
      af[tm] = *(const bf16x8*)(X + (size_t)row * CH + kk);
    }
    bf16x8 bfr[4];
#pragma unroll
    for (int tn = 0; tn < 4; tn++)
      bfr[tn] = *(const bf16x8*)&WT[n0w + tn * 16 + l16][quad * 8];
#pragma unroll
    for (int tm = 0; tm < 2; tm++)
#pragma unroll
      for (int tn = 0; tn < 4; tn++)
        acc[tm][tn] = __builtin_amdgcn_mfma_f32_16x16x32_bf16(af[tm], bfr[tn], acc[tm][tn], 0, 0, 0);
  }
#pragma unroll
  for (int tm = 0; tm < 2; tm++)
#pragma unroll
    for (int tn = 0; tn < 4; tn++) {
      int col = n0w + tn * 16 + l16;
      int rowb = m0 + tm * 16 + quad * 4;
#pragma unroll
      for (int r = 0; r < 4; r++) {
        int row = rowb + r;
        int g = row / FN, lr = row - g * FN;
        PT[((size_t)g * CH + col) * FN + lr] = f2bf(acc[tm][tn][r]);
      }
    }
}

// ------- agg layer 1: H = tanh(A(f32) @ P + b); emits bf16 Ab; pools into hp -------
// grid NG*6 XCD-swizzled; BM=64, BN=128.
__global__ __launch_bounds__(256) void k_agg1(
    const float* __restrict__ A32, const u16* __restrict__ PT,
    const float* __restrict__ bias, u16* __restrict__ Hout,
    u16* __restrict__ Ab, float* __restrict__ hp) {
  __shared__ float ps[8][128];
  int id = blockIdx.x;
  int g = (id & 7) + 8 * (id / 48);
  int mb = (id % 48) >> 3;
  int wid = threadIdx.x >> 6, lane = threadIdx.x & 63;
  int quad = lane >> 4, l16 = lane & 15;
  int m0 = mb * 64 + (wid & 1) * 32;
  int n0 = (wid >> 1) * 64;
  const float* Ag = A32 + (size_t)g * FN * FN;
  u16* Abg = Ab + (size_t)g * FN * FN;
  const u16* PTg = PT + (size_t)g * CH * FN;
  bool wr_ab = ((wid >> 1) == 0);               // n-half 0 waves own the Ab write
  f32x4 acc[2][4];
#pragma unroll
  for (int i = 0; i < 2; i++)
#pragma unroll
    for (int j = 0; j < 4; j++) acc[i][j] = (f32x4){0,0,0,0};
  for (int k0 = 0; k0 < FN; k0 += 32) {
    int kk = k0 + quad * 8;
    bool kin = kk < FN;
    bf16x8 af[2];
#pragma unroll
    for (int tm = 0; tm < 2; tm++) {
      int row = m0 + tm * 16 + l16;
      bf16x8 a = bzero8();
      if (kin && row < FN) {
        f32x4 va = *(const f32x4*)(Ag + (size_t)row * FN + kk);
        f32x4 vb = *(const f32x4*)(Ag + (size_t)row * FN + kk + 4);
#pragma unroll
        for (int j = 0; j < 4; j++) { a[j] = (short)f2bf(va[j]); a[4 + j] = (short)f2bf(vb[j]); }
        if (wr_ab) *(bf16x8*)(Abg + (size_t)row * FN + kk) = a;
      }
      af[tm] = a;
    }
    bf16x8 bfr[4];
#pragma unroll
    for (int tn = 0; tn < 4; tn++) {
      int col = n0 + tn * 16 + l16;
      bfr[tn] = kin ? *(const bf16x8*)(PTg + (size_t)col * FN + kk) : bzero8();
    }
#pragma unroll
    for (int tm = 0; tm < 2; tm++)
#pragma unroll
      for (int tn = 0; tn < 4; tn++)
        acc[tm][tn] = __builtin_amdgcn_mfma_f32_16x16x32_bf16(af[tm], bfr[tn], acc[tm][tn], 0, 0, 0);
  }
  float lsum[4] = {0.f, 0.f, 0.f, 0.f};
#pragma unroll
  for (int tm = 0; tm < 2; tm++)
#pragma unroll
    for (int tn = 0; tn < 4; tn++) {
      int col = n0 + tn * 16 + l16;
      float bc = bias[col];
      int rowb = m0 + tm * 16 + quad * 4;
#pragma unroll
      for (int r = 0; r < 4; r++) {
        int row = rowb + r;
        if (row < FN) {
          float t = tanhf(acc[tm][tn][r] + bc);
          Hout[(size_t)(g * FN + row) * CH + col] = f2bf(t);
          lsum[tn] += t;
        }
      }
    }
  int cid = (wid & 1) * 4 + quad;
#pragma unroll
  for (int tn = 0; tn < 4; tn++) ps[cid][n0 + tn * 16 + l16] = lsum[tn];
  __syncthreads();
  if (threadIdx.x < 128) {
    float s = 0.f;
#pragma unroll
    for (int c = 0; c < 8; c++) s += ps[c][threadIdx.x];
    atomicAdd(&hp[g * 384 + threadIdx.x], s);
  }
}

// ------- agg layers 2/3: A from bf16 Ab; Hout may be null (layer 3) -------
__global__ __launch_bounds__(256) void k_agg23(
    const u16* __restrict__ Ab, const u16* __restrict__ PT,
    const float* __restrict__ bias, u16* __restrict__ Hout,
    float* __restrict__ hp, int loff) {
  __shared__ float ps[8][128];
  int id = blockIdx.x;
  int g = (id & 7) + 8 * (id / 48);
  int mb = (id % 48) >> 3;
  int wid = threadIdx.x >> 6, lane = threadIdx.x & 63;
  int quad = lane >> 4, l16 = lane & 15;
  int m0 = mb * 64 + (wid & 1) * 32;
  int n0 = (wid >> 1) * 64;
  const u16* Abg = Ab + (size_t)g * FN * FN;
  const u16* PTg = PT + (size_t)g * CH * FN;
  f32x4 acc[2][4];
#pragma unroll
  for (int i = 0; i < 2; i++)
#pragma unroll
    for (int j = 0; j < 4; j++) acc[i][j] = (f32x4){0,0,0,0};
  for (int k0 = 0; k0 < FN; k0 += 32) {
    int kk = k0 + quad * 8;
    bool kin = kk < FN;
    bf16x8 af[2];
#pragma unroll
    for (int tm = 0; tm < 2; tm++) {
      int row = m0 + tm * 16 + l16;
      af[tm] = (kin && row < FN) ? *(const bf16x8*)(Abg + (size_t)row * FN + kk) : bzero8();
    }
    bf16x8 bfr[4];
#pragma unroll
    for (int tn = 0; tn < 4; tn++) {
      int col = n0 + tn * 16 + l16;
      bfr[tn] = kin ? *(const bf16x8*)(PTg + (size_t)col * FN + kk) : bzero8();
    }
#pragma unroll
    for (int tm = 0; tm < 2; tm++)
#pragma unroll
      for (int tn = 0; tn < 4; tn++)
        acc[tm][tn] = __builtin_amdgcn_mfma_f32_16x16x32_bf16(af[tm], bfr[tn], acc[tm][tn], 0, 0, 0);
  }
  float lsum[4] = {0.f, 0.f, 0.f, 0.f};
#pragma unroll
  for (int tm = 0; tm < 2; tm++)
#pragma unroll
    for (int tn = 0; tn < 4; tn++) {
      int col = n0 + tn * 16 + l16;
      float bc = bias[col];
      int rowb = m0 + tm * 16 + quad * 4;
#pragma unroll
      for (int r = 0; r < 4; r++) {
        int row = rowb + r;
        if (row < FN) {
          float t = tanhf(acc[tm][tn][r] + bc);
          if (Hout) Hout[(size_t)(g * FN + row) * CH + col] = f2bf(t);
          lsum[tn] += t;
        }
      }
    }
  int cid = (wid & 1) * 4 + quad;
#pragma unroll
  for (int tn = 0; tn < 4; tn++) ps[cid][n0 + tn * 16 + l16] = lsum[tn];
  __syncthreads();
  if (threadIdx.x < 128) {
    float s = 0.f;
#pragma unroll
    for (int c = 0; c < 8; c++) s += ps[c][threadIdx.x];
    atomicAdd(&hp[g * 384 + loff + threadIdx.x], s);
  }
}

// ------- big GEMM: part[s] = Z[128][chunk] @ W1[chunk][512], XCD-swizzled -------
__global__ __launch_bounds__(256) void k_gemm_big(
    const u16* __restrict__ Z, const float* __restrict__ W1f, float* __restrict__ part) {
  __shared__ __attribute__((aligned(16))) u16 WT[128][40];
  int id = blockIdx.x;                         // 0..511
  int s = (id & 7) + 8 * (id >> 5);
  int n0b = ((id >> 3) & 3) * 128;
  int wid = threadIdx.x >> 6, lane = threadIdx.x & 63;
  int quad = lane >> 4, l16 = lane & 15;
  int m0 = wid * 32;
  int kl = threadIdx.x >> 3, nseg = (threadIdx.x & 7) * 16;
  int kbeg = s * 512;
  int kend = (ZLD < kbeg + 512) ? ZLD : (kbeg + 512);
  f32x4 acc[2][8];
#pragma unroll
  for (int i = 0; i < 2; i++)
#pragma unroll
    for (int j = 0; j < 8; j++) acc[i][j] = (f32x4){0,0,0,0};
  for (int k0 = kbeg; k0 < kend; k0 += 32) {
    __syncthreads();
    int kg = k0 + kl;
    if (kg < D1) {
      const float* wrow = W1f + (size_t)kg * H1 + n0b + nseg;
      f32x4 w0 = *(const f32x4*)(wrow);
      f32x4 w1 = *(const f32x4*)(wrow + 4);
      f32x4 w2 = *(const f32x4*)(wrow + 8);
      f32x4 w3 = *(const f32x4*)(wrow + 12);
#pragma unroll
      for (int j = 0; j < 4; j++) {
        WT[nseg + j][kl]      = f2bf(w0[j]);
        WT[nseg + 4 + j][kl]  = f2bf(w1[j]);
        WT[nseg + 8 + j][kl]  = f2bf(w2[j]);
        WT[nseg + 12 + j][kl] = f2bf(w3[j]);
      }
    } else {
#pragma unroll
      for (int j = 0; j < 16; j++) WT[nseg + j][kl] = 0;
    }
    __syncthreads();
    int kk = k0 + quad * 8;
    bf16x8 af[2];
#pragma unroll
    for (int tm = 0; tm < 2; tm++) {
      int row = m0 + tm * 16 + l16;
      af[tm] = *(const bf16x8*)(Z + (size_t)row * ZLD + kk);
    }
    bf16x8 bfr[8];
#pragma unroll
    for (int tn = 0; tn < 8; tn++)
      bfr[tn] = *(const bf16x8*)&WT[tn * 16 + l16][quad * 8];
#pragma unroll
    for (int tm = 0; tm < 2; tm++)
#pragma unroll
      for (int tn = 0; tn < 8; tn++)
        acc[tm][tn] = __builtin_amdgcn_mfma_f32_16x16x32_bf16(af[tm], bfr[tn], acc[tm][tn], 0, 0, 0);
  }
#pragma unroll
  for (int tm = 0; tm < 2; tm++)
#pragma unroll
    for (int tn = 0; tn < 8; tn++) {
      int col = n0b + tn * 16 + l16;
      int rowb = m0 + tm * 16 + quad * 4;
#pragma unroll
      for (int r = 0; r < 4; r++)
        part[((size_t)s * NG + rowb + r) * H1 + col] = acc[tm][tn][r];
    }
}

__global__ void k_red(const float* __restrict__ part, float* __restrict__ y1) {
  int idx = blockIdx.x * 256 + threadIdx.x;       // < 65536
  float s = 0.f;
#pragma unroll 8
  for (int i = 0; i < NSPLIT; i++) s += part[(size_t)i * 65536 + idx];
  y1[idx] = s;                                    // bias dropped: BN cancels it
}

// BN + ReLU + bf16 cast: grid (N/64); block 256 = 64 channels x 4 row-groups of 32.
__global__ __launch_bounds__(256) void k_bnrelu(
    const float* __restrict__ y, const float* __restrict__ gam,
    const float* __restrict__ bet, u16* __restrict__ a, int N) {
  __shared__ float sb[4][64], sb2[4][64];
  int c63 = threadIdx.x & 63;
  int grp = threadIdx.x >> 6;
  int c = blockIdx.x * 64 + c63;
  float s = 0.f, ss = 0.f;
#pragma unroll 8
  for (int m = grp * 32; m < grp * 32 + 32; m++) {
    float v = y[(size_t)m * N + c]; s += v; ss += v * v;
  }
  sb[grp][c63] = s; sb2[grp][c63] = ss;
  __syncthreads();
  float S = sb[0][c63] + sb[1][c63] + sb[2][c63] + sb[3][c63];
  float SS = sb2[0][c63] + sb2[1][c63] + sb2[2][c63] + sb2[3][c63];
  float mean = S * (1.0f / NG);
  float var = fmaxf(SS * (1.0f / NG) - mean * mean, 0.f);
  float rstd = rsqrtf(var + EPS);
  float ga = gam[c] * rstd;
  float bb = bet[c] - mean * ga;
#pragma unroll 8
  for (int m = grp * 32; m < grp * 32 + 32; m++) {
    float v = y[(size_t)m * N + c] * ga + bb;
    a[(size_t)m * N + c] = f2bf(fmaxf(v, 0.f));
  }
}

// ------- fused MLP GEMM + BN + ReLU: a_out = relu(bn(A@W)) -------
__global__ __launch_bounds__(256) void k_mlpbn(
    const u16* __restrict__ A, const float* __restrict__ W,
    const float* __restrict__ gam, const float* __restrict__ bet,
    u16* __restrict__ aout, int K, int N) {
  __shared__ __attribute__((aligned(16))) u16 WT[64][40];
  __shared__ float rs[4][4][4][16], rss[4][4][4][16];   // [wid][quad][tn][l16]
  int wid = threadIdx.x >> 6, lane = threadIdx.x & 63;
  int quad = lane >> 4, l16 = lane & 15;
  int n0b = blockIdx.x * 64;
  int m0 = wid * 32;
  int kl = threadIdx.x >> 3;
  int nseg = (threadIdx.x & 7) * 8;
  f32x4 acc[2][4];
#pragma unroll
  for (int i = 0; i < 2; i++)
#pragma unroll
    for (int j = 0; j < 4; j++) acc[i][j] = (f32x4){0,0,0,0};
  for (int k0 = 0; k0 < K; k0 += 32) {
    __syncthreads();
    const float* wrow = W + (size_t)(k0 + kl) * N + n0b + nseg;
    f32x4 w0 = *(const f32x4*)(wrow);
    f32x4 w1 = *(const f32x4*)(wrow + 4);
#pragma unroll
    for (int j = 0; j < 4; j++) {
      WT[nseg + j][kl]     = f2bf(w0[j]);
      WT[nseg + 4 + j][kl] = f2bf(w1[j]);
    }
    __syncthreads();
    int kk = k0 + quad * 8;
    bf16x8 af[2];
#pragma unroll
    for (int tm = 0; tm < 2; tm++) {
      int row = m0 + tm * 16 + l16;
      af[tm] = *(const bf16x8*)(A + (size_t)row * K + kk);
    }
    bf16x8 bfr[4];
#pragma unroll
    for (int tn = 0; tn < 4; tn++)
      bfr[tn] = *(const bf16x8*)&WT[tn * 16 + l16][quad * 8];
#pragma unroll
    for (int tm = 0; tm < 2; tm++)
#pragma unroll
      for (int tn = 0; tn < 4; tn++)
        acc[tm][tn] = __builtin_amdgcn_mfma_f32_16x16x32_bf16(af[tm], bfr[tn], acc[tm][tn], 0, 0, 0);
  }
  __syncthreads();
#pragma unroll
  for (int tn = 0; tn < 4; tn++) {
    float s = 0.f, ss = 0.f;
#pragma unroll
    for (int tm = 0; tm < 2; tm++)
#pragma unroll
      for (int r = 0; r < 4; r++) { float v = acc[tm][tn][r]; s += v; ss += v * v; }
    rs[wid][quad][tn][l16] = s;
    rss[wid][quad][tn][l16] = ss;
  }
  __syncthreads();
#pragma unroll
  for (int tn = 0; tn < 4; tn++) {
    float S = 0.f, SS = 0.f;
#pragma unroll
    for (int w = 0; w < 4; w++)
#pragma unroll
      for (int q = 0; q < 4; q++) { S += rs[w][q][tn][l16]; SS += rss[w][q][tn][l16]; }
    float mean = S * (1.0f / NG);
    float var = fmaxf(SS * (1.0f / NG) - mean * mean, 0.f);
    float rstd = rsqrtf(var + EPS);
    int col = n0b + tn * 16 + l16;
    float ga = gam[col] * rstd;
    float bb = bet[col] - mean * ga;
#pragma unroll
    for (int tm = 0; tm < 2; tm++) {
      int rowb = m0 + tm * 16 + quad * 4;
#pragma unroll
      for (int r = 0; r < 4; r++) {
        float v = acc[tm][tn][r] * ga + bb;
        aout[(size_t)(rowb + r) * N + col] = f2bf(fmaxf(v, 0.f));
      }
    }
  }
}

// blocks 0..359: triu gather + BN of raw connectome -> z[:, 0:TRI)
// block 360: pooled-h BN (with 1/FN mean scaling) -> z[:, TRI:TRI+384) + zero pad
__global__ __launch_bounds__(256) void k_x0bn(
    const float* __restrict__ x, const float* __restrict__ gam,
    const float* __restrict__ bet, const float* __restrict__ hp,
    const float* __restrict__ hgam, const float* __restrict__ hbet,
    u16* __restrict__ z) {
  int i = blockIdx.x;
  if (i < FN) {
    int off = i * FN - (i * (i - 1)) / 2;
    for (int j = i + (int)threadIdx.x; j < FN; j += 256) {
      float s = 0.f, ss = 0.f;
#pragma unroll 8
      for (int b = 0; b < NG; b++) {
        float v = x[(size_t)(b * FN + i) * FN + j];
        s += v; ss += v * v;
      }
      float mean = s * (1.0f / NG);
      float var = fmaxf(ss * (1.0f / NG) - mean * mean, 0.f);
      float rstd = rsqrtf(var + EPS);
      int f = off + (j - i);
      float ga = gam[f] * rstd;
      float bb = bet[f] - mean * ga;
#pragma unroll 8
      for (int b = 0; b < NG; b++) {
        float v = x[(size_t)(b * FN + i) * FN + j];
        z[(size_t)b * ZLD + f] = f2bf(v * ga + bb);
      }
    }
  } else {
    for (int c = threadIdx.x; c < 384; c += 256) {
      float s = 0.f, ss = 0.f;
#pragma unroll 8
      for (int m = 0; m < NG; m++) {
        float v = hp[m * 384 + c] * (1.0f / FN);   // pooled sum -> mean
        s += v; ss += v * v;
      }
      float mean = s * (1.0f / NG);
      float var = fmaxf(ss * (1.0f / NG) - mean * mean, 0.f);
      float rstd = rsqrtf(var + EPS);
      float ga = hgam[c] * rstd;
      float bb = hbet[c] - mean * ga;
#pragma unroll 8
      for (int m = 0; m < NG; m++)
        z[(size_t)m * ZLD + TRI + c] = f2bf(hp[m * 384 + c] * (1.0f / FN) * ga + bb);
    }
    if (threadIdx.x < NG) {
      for (int t = 0; t < ZLD - D1; t++)
        z[(size_t)threadIdx.x * ZLD + D1 + t] = 0;
    }
  }
}

__global__ void k_head(const u16* __restrict__ a3, const float* __restrict__ W4,
                       const float* __restrict__ b4, float* __restrict__ out) {
  __shared__ float w4s[H2 * 2];
  int m = threadIdx.x;                            // block 128
  for (int i = m; i < H2 * 2; i += 128) w4s[i] = W4[i];
  __syncthreads();
  float a0 = b4[0], a1 = b4[1];
  for (int k0 = 0; k0 < H2; k0 += 8) {
    bf16x8 v = *(const bf16x8*)(a3 + (size_t)m * H2 + k0);
#pragma unroll
    for (int j = 0; j < 8; j++) {
      float f = bf2f((u16)v[j]);
      a0 += f * w4s[(k0 + j) * 2];
      a1 += f * w4s[(k0 + j) * 2 + 1];
    }
  }
  float mx = fmaxf(a0, a1);
  float lse = mx + logf(expf(a0 - mx) + expf(a1 - mx));
  out[m * 2]     = a0 - lse;
  out[m * 2 + 1] = a1 - lse;
}

// ---------------- launch ----------------
extern "C" void kernel_launch(void* const* d_in, const int* in_sizes, int n_in,
                              void* d_out, int out_size, void* d_ws, size_t ws_size,
                              hipStream_t stream) {
  const float* x    = (const float*)d_in[0];
  const int* esrc   = (const int*)d_in[1];
  const int* edst   = (const int*)d_in[2];
  // d_in[3] = batch (uniform; unused)
  const float* Wc1 = (const float*)d_in[4];  const float* bc1 = (const float*)d_in[5];
  const float* Wc2 = (const float*)d_in[6];  const float* bc2 = (const float*)d_in[7];
  const float* Wc3 = (const float*)d_in[8];  const float* bc3 = (const float*)d_in[9];
  const float* bn_g = (const float*)d_in[10]; const float* bn_b = (const float*)d_in[11];
  const float* bnh_g = (const float*)d_in[12]; const float* bnh_b = (const float*)d_in[13];
  const float* W1 = (const float*)d_in[14];
  const float* g1 = (const float*)d_in[16]; const float* be1 = (const float*)d_in[17];
  const float* W2 = (const float*)d_in[18];
  const float* g2 = (const float*)d_in[20]; const float* be2 = (const float*)d_in[21];
  const float* W3 = (const float*)d_in[22];
  const float* g3 = (const float*)d_in[24]; const float* be3 = (const float*)d_in[25];
  const float* W4 = (const float*)d_in[26]; const float* b4 = (const float*)d_in[27];

  char* ws = (char*)d_ws;
  float* A32  = (float*)(ws + A32_OFF);
  float* deg  = (float*)(ws + DEG_OFF);
  float* hp   = (float*)(ws + HP_OFF);
  u16*   Ab   = (u16*)(ws + AB_OFF);
  u16*   PT   = (u16*)(ws + PT_OFF);
  u16*   h    = (u16*)(ws + H_OFF);
  u16*   z    = (u16*)(ws + Z_OFF);
  float* part = (float*)(ws + PART_OFF);
  float* y1   = (float*)(ws + Y1_OFF);
  u16*   a1   = (u16*)(ws + A1_OFF);
  u16*   a2   = (u16*)(ws + A2_OFF);
  u16*   a3   = (u16*)(ws + A3_OFF);

  // one memset covers A32 + deg + hp (contiguous)
  (void)hipMemsetAsync(A32, 0, (size_t)NG * FN * FN * 4 + (size_t)NN * 4 + (size_t)NG * 384 * 4, stream);

  dim3 b256(256);
  k_deg<<<dim3((NE + 255) / 256), b256, 0, stream>>>(edst, deg);
  k_abuild<<<dim3((NE + NN + 255) / 256), b256, 0, stream>>>(esrc, edst, deg, A32);

  // GCN layers; pooling fused into agg epilogues (atomic into hp)
  k_gemm_xw_f32<<<dim3(NN / 64), b256, 0, stream>>>(x, Wc1, PT, FN);
  k_agg1<<<dim3(NG * 6), b256, 0, stream>>>(A32, PT, bc1, h, Ab, hp);
  k_gemm_xw_bf16<<<dim3(NN / 64), b256, 0, stream>>>(h, Wc2, PT);
  k_agg23<<<dim3(NG * 6), b256, 0, stream>>>(Ab, PT, bc2, h, hp, CH);
  k_gemm_xw_bf16<<<dim3(NN / 64), b256, 0, stream>>>(h, Wc3, PT);
  k_agg23<<<dim3(NG * 6), b256, 0, stream>>>(Ab, PT, bc3, (u16*)nullptr, hp, 2 * CH);

  // feature assembly (z aliases A32 region — A32 dead after k_agg1)
  k_x0bn<<<dim3(FN + 1), b256, 0, stream>>>(x, bn_g, bn_b, hp, bnh_g, bnh_b, z);

  // MLP head
  k_gemm_big<<<dim3(512), b256, 0, stream>>>(z, W1, part);
  k_red<<<dim3(65536 / 256), b256, 0, stream>>>(part, y1);
  k_bnrelu<<<dim3(H1 / 64), b256, 0, stream>>>(y1, g1, be1, a1, H1);
  k_mlpbn<<<dim3(H2 / 64), b256, 0, stream>>>(a1, W2, g2, be2, a2, H1, H2);
  k_mlpbn<<<dim3(H2 / 64), b256, 0, stream>>>(a2, W3, g3, be3, a3, H2, H2);
  k_head<<<dim3(1), dim3(128), 0, stream>>>(a3, W4, b4, (float*)d_out);
}